// Round 1
// baseline (7350.076 us; speedup 1.0000x reference)
//
#include <hip/hip_runtime.h>
#include <math.h>

#define N_NODES 50000
#define NE      800000
#define INC     128
#define F1      128     // HEADS*HID
#define HEADS   8
#define HID     16
#define OUTC    16
#define NEG     0.2f
#define ETOT    (NE + N_NODES)   // edges + self loops

__device__ __forceinline__ void atomicMaxF(float* a, float v) {
    // works for all finite floats + -inf init
    if (v >= 0.0f) atomicMax((int*)a, __float_as_int(v));
    else           atomicMin((unsigned int*)a, __float_as_uint(v));
}

__global__ void fill_kernel(float* __restrict__ p, int n, float v) {
    int i = blockIdx.x * blockDim.x + threadIdx.x;
    if (i < n) p[i] = v;
}

// ---------------- Layer 1: GEMM (x @ W1) + attention logits ----------------
__global__ __launch_bounds__(128) void node1_kernel(
    const float* __restrict__ x, const float* __restrict__ W1,
    const float* __restrict__ a_src, const float* __restrict__ a_dst,
    float* __restrict__ hfeat, float* __restrict__ als, float* __restrict__ ald)
{
    __shared__ float Wl[INC * F1];           // 64 KB
    int j = threadIdx.x;                     // output column 0..127
    for (int idx = j; idx < INC * F1; idx += 128) Wl[idx] = W1[idx];
    float asj = a_src[j];                    // flat [HEADS*HID] == column j
    float adj = a_dst[j];
    __syncthreads();

    for (int n = blockIdx.x; n < N_NODES; n += gridDim.x) {
        const float4* xr = (const float4*)(x + (size_t)n * INC);
        float acc0 = 0.f, acc1 = 0.f, acc2 = 0.f, acc3 = 0.f;
        #pragma unroll
        for (int k4 = 0; k4 < 32; ++k4) {
            float4 xv = xr[k4];              // wave-uniform broadcast load
            int k = k4 * 4;
            acc0 += xv.x * Wl[(k + 0) * F1 + j];
            acc1 += xv.y * Wl[(k + 1) * F1 + j];
            acc2 += xv.z * Wl[(k + 2) * F1 + j];
            acc3 += xv.w * Wl[(k + 3) * F1 + j];
        }
        float h = (acc0 + acc1) + (acc2 + acc3);
        hfeat[(size_t)n * F1 + j] = h;
        // per-head dot with a_src/a_dst: reduce groups of 16 lanes
        float ps = h * asj, pd = h * adj;
        for (int off = 8; off; off >>= 1) {
            ps += __shfl_down(ps, off, 16);
            pd += __shfl_down(pd, off, 16);
        }
        if ((j & 15) == 0) {
            als[n * HEADS + (j >> 4)] = ps;
            ald[n * HEADS + (j >> 4)] = pd;
        }
    }
}

// ---------------- Layer 1 edge passes ----------------
__global__ void edge_max1(const int* __restrict__ ei,
                          const float* __restrict__ als, const float* __restrict__ ald,
                          float* __restrict__ m)
{
    int tid = blockIdx.x * blockDim.x + threadIdx.x;
    if (tid >= ETOT * HEADS) return;
    int e = tid >> 3, h = tid & 7;
    int s, d;
    if (e < NE) { s = ei[e]; d = ei[NE + e]; } else { s = e - NE; d = s; }
    float v = als[s * 8 + h] + ald[d * 8 + h];
    v = v > 0.f ? v : NEG * v;
    atomicMaxF(&m[d * 8 + h], v);
}

__global__ void edge_agg1(const int* __restrict__ ei,
                          const float* __restrict__ als, const float* __restrict__ ald,
                          const float* __restrict__ m, const float* __restrict__ hfeat,
                          float* __restrict__ denom, float* __restrict__ acc)
{
    int tid = blockIdx.x * blockDim.x + threadIdx.x;
    if (tid >= ETOT * HEADS) return;
    int e = tid >> 3, h = tid & 7;
    int s, d;
    if (e < NE) { s = ei[e]; d = ei[NE + e]; } else { s = e - NE; d = s; }
    float v = als[s * 8 + h] + ald[d * 8 + h];
    v = v > 0.f ? v : NEG * v;
    float w = __expf(v - m[d * 8 + h]);
    atomicAdd(&denom[d * 8 + h], w);
    const float4* hs = (const float4*)(hfeat + (size_t)s * F1 + h * 16);
    float* ap = acc + (size_t)d * F1 + h * 16;
    #pragma unroll
    for (int i = 0; i < 4; ++i) {
        float4 hv = hs[i];
        atomicAdd(ap + i * 4 + 0, w * hv.x);
        atomicAdd(ap + i * 4 + 1, w * hv.y);
        atomicAdd(ap + i * 4 + 2, w * hv.z);
        atomicAdd(ap + i * 4 + 3, w * hv.w);
    }
}

// normalize + bias + ELU  (writes over h1 buffer)
__global__ void norm1_kernel(const float* __restrict__ acc, const float* __restrict__ denom,
                             const float* __restrict__ b1, float* __restrict__ hout)
{
    int tid = blockIdx.x * blockDim.x + threadIdx.x;
    if (tid >= N_NODES * F1) return;
    int n = tid >> 7, j = tid & 127;
    float v = acc[tid] / denom[n * 8 + (j >> 4)] + b1[j];
    hout[tid] = v > 0.f ? v : (__expf(v) - 1.0f);
}

// ---------------- Layer 2: GEMM (h1 @ W2) + logits ----------------
__global__ __launch_bounds__(256) void node2_kernel(
    const float* __restrict__ h1, const float* __restrict__ W2,
    const float* __restrict__ a_s, const float* __restrict__ a_d,
    float* __restrict__ h2, float* __restrict__ als2, float* __restrict__ ald2)
{
    __shared__ float W2l[F1 * OUTC];   // 8 KB
    for (int i = threadIdx.x; i < F1 * OUTC; i += 256) W2l[i] = W2[i];
    __syncthreads();
    int n = blockIdx.x * blockDim.x + threadIdx.x;
    if (n >= N_NODES) return;

    float o[OUTC];
    #pragma unroll
    for (int c = 0; c < OUTC; ++c) o[c] = 0.f;
    const float4* xr = (const float4*)(h1 + (size_t)n * F1);
    for (int k4 = 0; k4 < 32; ++k4) {
        float4 xv = xr[k4];
        int k = k4 * 4;
        #pragma unroll
        for (int c = 0; c < OUTC; ++c) {
            o[c] += xv.x * W2l[(k + 0) * OUTC + c] + xv.y * W2l[(k + 1) * OUTC + c]
                  + xv.z * W2l[(k + 2) * OUTC + c] + xv.w * W2l[(k + 3) * OUTC + c];
        }
    }
    float4* h2o = (float4*)(h2 + (size_t)n * OUTC);
    #pragma unroll
    for (int c4 = 0; c4 < 4; ++c4) {
        float4 v; v.x = o[c4*4]; v.y = o[c4*4+1]; v.z = o[c4*4+2]; v.w = o[c4*4+3];
        h2o[c4] = v;
    }
    float ps = 0.f, pd = 0.f;
    #pragma unroll
    for (int c = 0; c < OUTC; ++c) { ps += o[c] * a_s[c]; pd += o[c] * a_d[c]; }
    als2[n] = ps; ald2[n] = pd;
}

// ---------------- Layer 2 edge passes ----------------
__global__ void edge_max2(const int* __restrict__ ei,
                          const float* __restrict__ als, const float* __restrict__ ald,
                          float* __restrict__ m)
{
    int e = blockIdx.x * blockDim.x + threadIdx.x;
    if (e >= ETOT) return;
    int s, d;
    if (e < NE) { s = ei[e]; d = ei[NE + e]; } else { s = e - NE; d = s; }
    float v = als[s] + ald[d];
    v = v > 0.f ? v : NEG * v;
    atomicMaxF(&m[d], v);
}

__global__ void edge_agg2(const int* __restrict__ ei,
                          const float* __restrict__ als, const float* __restrict__ ald,
                          const float* __restrict__ m, const float* __restrict__ h2,
                          float* __restrict__ denom, float* __restrict__ acc)
{
    int e = blockIdx.x * blockDim.x + threadIdx.x;
    if (e >= ETOT) return;
    int s, d;
    if (e < NE) { s = ei[e]; d = ei[NE + e]; } else { s = e - NE; d = s; }
    float v = als[s] + ald[d];
    v = v > 0.f ? v : NEG * v;
    float w = __expf(v - m[d]);
    atomicAdd(&denom[d], w);
    const float4* hs = (const float4*)(h2 + (size_t)s * OUTC);
    float* ap = acc + (size_t)d * OUTC;
    #pragma unroll
    for (int i = 0; i < 4; ++i) {
        float4 hv = hs[i];
        atomicAdd(ap + i * 4 + 0, w * hv.x);
        atomicAdd(ap + i * 4 + 1, w * hv.y);
        atomicAdd(ap + i * 4 + 2, w * hv.z);
        atomicAdd(ap + i * 4 + 3, w * hv.w);
    }
}

__global__ void final_kernel(const float* __restrict__ acc, const float* __restrict__ denom,
                             const float* __restrict__ b2, float* __restrict__ out)
{
    int tid = blockIdx.x * blockDim.x + threadIdx.x;
    if (tid >= N_NODES * OUTC) return;
    int n = tid >> 4, c = tid & 15;
    out[tid] = acc[tid] / denom[n] + b2[c];
}

extern "C" void kernel_launch(void* const* d_in, const int* in_sizes, int n_in,
                              void* d_out, int out_size, void* d_ws, size_t ws_size,
                              hipStream_t stream)
{
    const float* x   = (const float*)d_in[0];
    const int*   ei  = (const int*)  d_in[1];
    const float* W1  = (const float*)d_in[2];
    const float* as1 = (const float*)d_in[3];
    const float* ad1 = (const float*)d_in[4];
    const float* b1  = (const float*)d_in[5];
    const float* W2  = (const float*)d_in[6];
    const float* as2 = (const float*)d_in[7];
    const float* ad2 = (const float*)d_in[8];
    const float* b2  = (const float*)d_in[9];
    float* out = (float*)d_out;

    // workspace layout (floats), ~64.8 MB total
    float* ws   = (float*)d_ws;
    float* h1   = ws;                                  // N*128 (reused for ELU output)
    float* als1 = h1   + (size_t)N_NODES * F1;         // N*8
    float* ald1 = als1 + N_NODES * HEADS;              // N*8
    float* h2f  = ald1 + N_NODES * HEADS;              // N*16
    float* als2 = h2f  + N_NODES * OUTC;               // N
    float* ald2 = als2 + N_NODES;                      // N
    float* m1   = ald2 + N_NODES;                      // N*8  -> -inf
    float* m2   = m1   + N_NODES * HEADS;              // N    -> -inf
    float* den1 = m2   + N_NODES;                      // N*8  -> 0
    float* den2 = den1 + N_NODES * HEADS;              // N    -> 0
    float* acc1 = den2 + N_NODES;                      // N*128 -> 0
    float* acc2 = acc1 + (size_t)N_NODES * F1;         // N*16  -> 0

    int ninf = N_NODES * HEADS + N_NODES;              // m1 + m2 contiguous
    fill_kernel<<<(ninf + 255) / 256, 256, 0, stream>>>(m1, ninf, -INFINITY);
    size_t zcnt = (size_t)N_NODES * HEADS + N_NODES
                + (size_t)N_NODES * F1 + (size_t)N_NODES * OUTC; // den1,den2,acc1,acc2 contiguous
    hipMemsetAsync(den1, 0, zcnt * sizeof(float), stream);

    node1_kernel<<<1024, 128, 0, stream>>>(x, W1, as1, ad1, h1, als1, ald1);

    long long t1 = (long long)ETOT * HEADS;
    edge_max1<<<(int)((t1 + 255) / 256), 256, 0, stream>>>(ei, als1, ald1, m1);
    edge_agg1<<<(int)((t1 + 255) / 256), 256, 0, stream>>>(ei, als1, ald1, m1, h1, den1, acc1);

    norm1_kernel<<<(N_NODES * F1 + 255) / 256, 256, 0, stream>>>(acc1, den1, b1, h1);

    node2_kernel<<<(N_NODES + 255) / 256, 256, 0, stream>>>(h1, W2, as2, ad2, h2f, als2, ald2);

    edge_max2<<<(ETOT + 255) / 256, 256, 0, stream>>>(ei, als2, ald2, m2);
    edge_agg2<<<(ETOT + 255) / 256, 256, 0, stream>>>(ei, als2, ald2, m2, h2f, den2, acc2);

    final_kernel<<<(N_NODES * OUTC + 255) / 256, 256, 0, stream>>>(acc2, den2, b2, out);
}

// Round 2
// 485.003 us; speedup vs baseline: 15.1547x; 15.1547x over previous
//
#include <hip/hip_runtime.h>
#include <math.h>

#define N_NODES 50000
#define NE      800000
#define INC     128
#define F1      128     // HEADS*HID
#define HEADS   8
#define HID     16
#define OUTC    16
#define NEG     0.2f
#define NB_SCAN ((N_NODES + 255) / 256)   // 196 blocks, fits single-block 2nd-level scan

// ---------------- CSR build (sort edges by dst, zero float atomics later) ---
__global__ void count_deg(const int* __restrict__ ei, int* __restrict__ deg) {
    int e = blockIdx.x * blockDim.x + threadIdx.x;
    if (e < NE) atomicAdd(&deg[ei[NE + e]], 1);
}

__global__ void scan_blocks(const int* __restrict__ deg, int* __restrict__ part,
                            int* __restrict__ bsums) {
    __shared__ int tmp[256];
    int tid = threadIdx.x;
    int i = blockIdx.x * 256 + tid;
    int v = (i < N_NODES) ? deg[i] : 0;
    tmp[tid] = v; __syncthreads();
    for (int off = 1; off < 256; off <<= 1) {
        int t = (tid >= off) ? tmp[tid - off] : 0;
        __syncthreads();
        tmp[tid] += t;
        __syncthreads();
    }
    if (i < N_NODES) part[i] = tmp[tid] - v;          // exclusive
    if (tid == 255) bsums[blockIdx.x] = tmp[255];
}

__global__ void scan_sums(int* __restrict__ bsums) {  // NB_SCAN <= 256
    __shared__ int tmp[256];
    int tid = threadIdx.x;
    int v = (tid < NB_SCAN) ? bsums[tid] : 0;
    tmp[tid] = v; __syncthreads();
    for (int off = 1; off < 256; off <<= 1) {
        int t = (tid >= off) ? tmp[tid - off] : 0;
        __syncthreads();
        tmp[tid] += t;
        __syncthreads();
    }
    if (tid < NB_SCAN) bsums[tid] = tmp[tid] - v;     // exclusive
}

__global__ void scan_finish(const int* __restrict__ part, const int* __restrict__ bsums,
                            int* __restrict__ rowstart, int* __restrict__ cursor) {
    int i = blockIdx.x * 256 + threadIdx.x;
    if (i < N_NODES) {
        int r = part[i] + bsums[blockIdx.x];
        rowstart[i] = r;
        cursor[i]   = r;
    }
    if (i == 0) rowstart[N_NODES] = NE;
}

__global__ void scatter_edges(const int* __restrict__ ei, int* __restrict__ cursor,
                              int* __restrict__ csr) {
    int e = blockIdx.x * blockDim.x + threadIdx.x;
    if (e < NE) {
        int d = ei[NE + e];
        int p = atomicAdd(&cursor[d], 1);
        csr[p] = ei[e];
    }
}

// ---------------- Layer 1: GEMM (x @ W1) + attention logits ----------------
__global__ __launch_bounds__(128) void node1_kernel(
    const float* __restrict__ x, const float* __restrict__ W1,
    const float* __restrict__ a_src, const float* __restrict__ a_dst,
    float* __restrict__ hfeat, float* __restrict__ als, float* __restrict__ ald)
{
    __shared__ float Wl[INC * F1];           // 64 KB
    int j = threadIdx.x;                     // output column 0..127
    for (int idx = j; idx < INC * F1; idx += 128) Wl[idx] = W1[idx];
    float asj = a_src[j];
    float adj = a_dst[j];
    __syncthreads();

    for (int n = blockIdx.x; n < N_NODES; n += gridDim.x) {
        const float4* xr = (const float4*)(x + (size_t)n * INC);
        float acc0 = 0.f, acc1 = 0.f, acc2 = 0.f, acc3 = 0.f;
        #pragma unroll
        for (int k4 = 0; k4 < 32; ++k4) {
            float4 xv = xr[k4];              // wave-uniform broadcast load
            int k = k4 * 4;
            acc0 += xv.x * Wl[(k + 0) * F1 + j];
            acc1 += xv.y * Wl[(k + 1) * F1 + j];
            acc2 += xv.z * Wl[(k + 2) * F1 + j];
            acc3 += xv.w * Wl[(k + 3) * F1 + j];
        }
        float h = (acc0 + acc1) + (acc2 + acc3);
        hfeat[(size_t)n * F1 + j] = h;
        float ps = h * asj, pd = h * adj;
        for (int off = 8; off; off >>= 1) {
            ps += __shfl_down(ps, off, 16);
            pd += __shfl_down(pd, off, 16);
        }
        if ((j & 15) == 0) {
            als[n * HEADS + (j >> 4)] = ps;
            ald[n * HEADS + (j >> 4)] = pd;
        }
    }
}

// ------ Layer 1 fused gather: online softmax + aggregate + bias + ELU ------
// one block (128 threads) per dst node; lane j handles feature j, head j>>4
__global__ __launch_bounds__(128) void agg1_kernel(
    const int* __restrict__ rowstart, const int* __restrict__ csr,
    const float* __restrict__ h1, const float* __restrict__ als,
    const float* __restrict__ ald, const float* __restrict__ b1,
    float* __restrict__ hout)
{
    int n = blockIdx.x;
    int j = threadIdx.x, h = j >> 4;
    float aldn = ald[n * HEADS + h];
    // self-loop seeds the online softmax: m = v_self, sum = 1, acc = h_self
    float v0 = als[n * HEADS + h] + aldn;
    v0 = v0 > 0.f ? v0 : NEG * v0;
    float m = v0, sum = 1.0f;
    float acc = h1[(size_t)n * F1 + j];
    int r0 = rowstart[n], r1 = rowstart[n + 1];
    for (int k = r0; k < r1; ++k) {
        int s = csr[k];
        float v = als[s * HEADS + h] + aldn;
        v = v > 0.f ? v : NEG * v;
        float hv = h1[(size_t)s * F1 + j];
        float nm = fmaxf(m, v);
        float sc = __expf(m - nm);
        float w  = __expf(v - nm);
        sum = sum * sc + w;
        acc = acc * sc + w * hv;
        m = nm;
    }
    float val = acc / sum + b1[j];
    hout[(size_t)n * F1 + j] = val > 0.f ? val : (__expf(val) - 1.0f);
}

// ---------------- Layer 2: GEMM (h1 @ W2) + logits ----------------
__global__ __launch_bounds__(256) void node2_kernel(
    const float* __restrict__ h1, const float* __restrict__ W2,
    const float* __restrict__ a_s, const float* __restrict__ a_d,
    float* __restrict__ h2, float* __restrict__ als2, float* __restrict__ ald2)
{
    __shared__ float W2l[F1 * OUTC];   // 8 KB
    for (int i = threadIdx.x; i < F1 * OUTC; i += 256) W2l[i] = W2[i];
    __syncthreads();
    int n = blockIdx.x * blockDim.x + threadIdx.x;
    if (n >= N_NODES) return;

    float o[OUTC];
    #pragma unroll
    for (int c = 0; c < OUTC; ++c) o[c] = 0.f;
    const float4* xr = (const float4*)(h1 + (size_t)n * F1);
    for (int k4 = 0; k4 < 32; ++k4) {
        float4 xv = xr[k4];
        int k = k4 * 4;
        #pragma unroll
        for (int c = 0; c < OUTC; ++c) {
            o[c] += xv.x * W2l[(k + 0) * OUTC + c] + xv.y * W2l[(k + 1) * OUTC + c]
                  + xv.z * W2l[(k + 2) * OUTC + c] + xv.w * W2l[(k + 3) * OUTC + c];
        }
    }
    float4* h2o = (float4*)(h2 + (size_t)n * OUTC);
    #pragma unroll
    for (int c4 = 0; c4 < 4; ++c4) {
        float4 v; v.x = o[c4*4]; v.y = o[c4*4+1]; v.z = o[c4*4+2]; v.w = o[c4*4+3];
        h2o[c4] = v;
    }
    float ps = 0.f, pd = 0.f;
    #pragma unroll
    for (int c = 0; c < OUTC; ++c) { ps += o[c] * a_s[c]; pd += o[c] * a_d[c]; }
    als2[n] = ps; ald2[n] = pd;
}

// ------ Layer 2 fused gather: 16 lanes per node, 16 nodes per block --------
__global__ __launch_bounds__(256) void agg2_kernel(
    const int* __restrict__ rowstart, const int* __restrict__ csr,
    const float* __restrict__ h2, const float* __restrict__ als,
    const float* __restrict__ ald, const float* __restrict__ b2,
    float* __restrict__ out)
{
    int g = threadIdx.x >> 4, c = threadIdx.x & 15;
    int n = blockIdx.x * 16 + g;
    if (n >= N_NODES) return;
    float aldn = ald[n];
    float v0 = als[n] + aldn;
    v0 = v0 > 0.f ? v0 : NEG * v0;
    float m = v0, sum = 1.0f;
    float acc = h2[(size_t)n * OUTC + c];
    int r0 = rowstart[n], r1 = rowstart[n + 1];
    for (int k = r0; k < r1; ++k) {
        int s = csr[k];
        float v = als[s] + aldn;
        v = v > 0.f ? v : NEG * v;
        float hv = h2[(size_t)s * OUTC + c];
        float nm = fmaxf(m, v);
        float sc = __expf(m - nm);
        float w  = __expf(v - nm);
        sum = sum * sc + w;
        acc = acc * sc + w * hv;
        m = nm;
    }
    out[(size_t)n * OUTC + c] = acc / sum + b2[c];
}

extern "C" void kernel_launch(void* const* d_in, const int* in_sizes, int n_in,
                              void* d_out, int out_size, void* d_ws, size_t ws_size,
                              hipStream_t stream)
{
    const float* x   = (const float*)d_in[0];
    const int*   ei  = (const int*)  d_in[1];
    const float* W1  = (const float*)d_in[2];
    const float* as1 = (const float*)d_in[3];
    const float* ad1 = (const float*)d_in[4];
    const float* b1  = (const float*)d_in[5];
    const float* W2  = (const float*)d_in[6];
    const float* as2 = (const float*)d_in[7];
    const float* ad2 = (const float*)d_in[8];
    const float* b2  = (const float*)d_in[9];
    float* out = (float*)d_out;

    // workspace carve-up (all 4-byte elements), ~62 MB
    float* ws   = (float*)d_ws;
    float* h1   = ws;                                  // N*128
    float* h1b  = h1   + (size_t)N_NODES * F1;         // N*128 (post-softmax ELU'd)
    float* als1 = h1b  + (size_t)N_NODES * F1;         // N*8
    float* ald1 = als1 + N_NODES * HEADS;              // N*8
    float* h2f  = ald1 + N_NODES * HEADS;              // N*16
    float* als2 = h2f  + N_NODES * OUTC;               // N
    float* ald2 = als2 + N_NODES;                      // N
    int*   deg  = (int*)(ald2 + N_NODES);              // N
    int*   rowstart = deg + N_NODES;                   // N+1
    int*   cursor   = rowstart + N_NODES + 1;          // N
    int*   part     = cursor + N_NODES;                // N
    int*   bsums    = part + N_NODES;                  // 256
    int*   csr      = bsums + 256;                     // NE

    // ---- CSR build (shared by both layers; graph is identical) ----
    hipMemsetAsync(deg, 0, N_NODES * sizeof(int), stream);
    count_deg<<<(NE + 255) / 256, 256, 0, stream>>>(ei, deg);
    scan_blocks<<<NB_SCAN, 256, 0, stream>>>(deg, part, bsums);
    scan_sums<<<1, 256, 0, stream>>>(bsums);
    scan_finish<<<NB_SCAN, 256, 0, stream>>>(part, bsums, rowstart, cursor);
    scatter_edges<<<(NE + 255) / 256, 256, 0, stream>>>(ei, cursor, csr);

    // ---- layer 1 ----
    node1_kernel<<<1024, 128, 0, stream>>>(x, W1, as1, ad1, h1, als1, ald1);
    agg1_kernel<<<N_NODES, 128, 0, stream>>>(rowstart, csr, h1, als1, ald1, b1, h1b);

    // ---- layer 2 ----
    node2_kernel<<<(N_NODES + 255) / 256, 256, 0, stream>>>(h1b, W2, as2, ad2, h2f, als2, ald2);
    agg2_kernel<<<(N_NODES + 15) / 16, 256, 0, stream>>>(rowstart, csr, h2f, als2, ald2, b2, out);
}

// Round 3
// 353.124 us; speedup vs baseline: 20.8144x; 1.3735x over previous
//
#include <hip/hip_runtime.h>
#include <math.h>

#define N_NODES 50000
#define NE      800000
#define INC     128
#define F1      128     // HEADS*HID
#define HEADS   8
#define HID     16
#define OUTC    16
#define NEG     0.2f
#define NB_SCAN ((N_NODES + 255) / 256)   // 196 blocks, fits single-block 2nd-level scan

// ---------------- CSR build (sort edges by dst) ----------------
__global__ void count_deg(const int* __restrict__ ei, int* __restrict__ deg) {
    int e = blockIdx.x * blockDim.x + threadIdx.x;
    if (e < NE) atomicAdd(&deg[ei[NE + e]], 1);
}

__global__ void scan_blocks(const int* __restrict__ deg, int* __restrict__ part,
                            int* __restrict__ bsums) {
    __shared__ int tmp[256];
    int tid = threadIdx.x;
    int i = blockIdx.x * 256 + tid;
    int v = (i < N_NODES) ? deg[i] : 0;
    tmp[tid] = v; __syncthreads();
    for (int off = 1; off < 256; off <<= 1) {
        int t = (tid >= off) ? tmp[tid - off] : 0;
        __syncthreads();
        tmp[tid] += t;
        __syncthreads();
    }
    if (i < N_NODES) part[i] = tmp[tid] - v;          // exclusive
    if (tid == 255) bsums[blockIdx.x] = tmp[255];
}

__global__ void scan_sums(int* __restrict__ bsums) {  // NB_SCAN <= 256
    __shared__ int tmp[256];
    int tid = threadIdx.x;
    int v = (tid < NB_SCAN) ? bsums[tid] : 0;
    tmp[tid] = v; __syncthreads();
    for (int off = 1; off < 256; off <<= 1) {
        int t = (tid >= off) ? tmp[tid - off] : 0;
        __syncthreads();
        tmp[tid] += t;
        __syncthreads();
    }
    if (tid < NB_SCAN) bsums[tid] = tmp[tid] - v;     // exclusive
}

__global__ void scan_finish(const int* __restrict__ part, const int* __restrict__ bsums,
                            int* __restrict__ rowstart, int* __restrict__ cursor) {
    int i = blockIdx.x * 256 + threadIdx.x;
    if (i < N_NODES) {
        int r = part[i] + bsums[blockIdx.x];
        rowstart[i] = r;
        cursor[i]   = r;
    }
    if (i == 0) rowstart[N_NODES] = NE;
}

__global__ void scatter_edges(const int* __restrict__ ei, int* __restrict__ cursor,
                              int* __restrict__ csr) {
    int e = blockIdx.x * blockDim.x + threadIdx.x;
    if (e < NE) {
        int d = ei[NE + e];
        int p = atomicAdd(&cursor[d], 1);
        csr[p] = ei[e];
    }
}

// ---------------- Layer 1: register-blocked GEMM (x @ W1) + logits ----------
// 256 threads: lane (tid&31) covers cols 4*(tid&31)..+3; grp (tid>>5) covers
// nodes n0 + grp*4 .. +3.  32 nodes per tile, 4x4 f32 accumulators/thread.
__global__ __launch_bounds__(256) void node1_kernel(
    const float* __restrict__ x, const float* __restrict__ W1,
    const float* __restrict__ a_src, const float* __restrict__ a_dst,
    float* __restrict__ hfeat, float* __restrict__ als, float* __restrict__ ald)
{
    __shared__ float Wl[INC * F1];      // 64 KB
    __shared__ float Xs[32 * INC];      // 16 KB
    int tid = threadIdx.x;
    for (int idx = tid; idx < INC * F1 / 4; idx += 256)
        ((float4*)Wl)[idx] = ((const float4*)W1)[idx];
    int cb  = (tid & 31) * 4;           // column base
    int grp = tid >> 5;                 // 0..7
    float4 as4 = *(const float4*)(a_src + cb);
    float4 ad4 = *(const float4*)(a_dst + cb);

    const int ntiles = (N_NODES + 31) / 32;
    for (int tile = blockIdx.x; tile < ntiles; tile += gridDim.x) {
        int n0 = tile * 32;
        __syncthreads();                 // Xs readers from prev iter done; also covers Wl init
        for (int idx = tid; idx < 32 * INC / 4; idx += 256) {
            int row = idx >> 5;          // 32 float4 per row
            int n = n0 + row;
            float4 v = (n < N_NODES) ? ((const float4*)(x + (size_t)n * INC))[idx & 31]
                                     : make_float4(0.f, 0.f, 0.f, 0.f);
            ((float4*)Xs)[idx] = v;
        }
        __syncthreads();

        float4 acc[4];
        #pragma unroll
        for (int m = 0; m < 4; ++m) acc[m] = make_float4(0.f, 0.f, 0.f, 0.f);

        #pragma unroll 4
        for (int k4 = 0; k4 < 32; ++k4) {
            int k = k4 * 4;
            float4 w0 = *(const float4*)(Wl + (k + 0) * F1 + cb);
            float4 w1 = *(const float4*)(Wl + (k + 1) * F1 + cb);
            float4 w2 = *(const float4*)(Wl + (k + 2) * F1 + cb);
            float4 w3 = *(const float4*)(Wl + (k + 3) * F1 + cb);
            #pragma unroll
            for (int m = 0; m < 4; ++m) {
                float4 xv = *(const float4*)(Xs + (grp * 4 + m) * INC + k);
                acc[m].x += xv.x * w0.x + xv.y * w1.x + xv.z * w2.x + xv.w * w3.x;
                acc[m].y += xv.x * w0.y + xv.y * w1.y + xv.z * w2.y + xv.w * w3.y;
                acc[m].z += xv.x * w0.z + xv.y * w1.z + xv.z * w2.z + xv.w * w3.z;
                acc[m].w += xv.x * w0.w + xv.y * w1.w + xv.z * w2.w + xv.w * w3.w;
            }
        }

        #pragma unroll
        for (int m = 0; m < 4; ++m) {
            int n = n0 + grp * 4 + m;
            if (n < N_NODES) {           // uniform within each 4-lane shuffle group
                *(float4*)(hfeat + (size_t)n * F1 + cb) = acc[m];
                float ps = acc[m].x * as4.x + acc[m].y * as4.y + acc[m].z * as4.z + acc[m].w * as4.w;
                float pd = acc[m].x * ad4.x + acc[m].y * ad4.y + acc[m].z * ad4.z + acc[m].w * ad4.w;
                ps += __shfl_down(ps, 1, 4); ps += __shfl_down(ps, 2, 4);
                pd += __shfl_down(pd, 1, 4); pd += __shfl_down(pd, 2, 4);
                if ((tid & 3) == 0) {
                    int head = (tid & 31) >> 2;
                    als[n * HEADS + head] = ps;
                    ald[n * HEADS + head] = pd;
                }
            }
        }
    }
}

// ------ Layer 1 fused gather: online softmax + aggregate + bias + ELU ------
__global__ __launch_bounds__(128) void agg1_kernel(
    const int* __restrict__ rowstart, const int* __restrict__ csr,
    const float* __restrict__ h1, const float* __restrict__ als,
    const float* __restrict__ ald, const float* __restrict__ b1,
    float* __restrict__ hout)
{
    int n = blockIdx.x;
    int j = threadIdx.x, h = j >> 4;
    float aldn = ald[n * HEADS + h];
    float v0 = als[n * HEADS + h] + aldn;
    v0 = v0 > 0.f ? v0 : NEG * v0;
    float m = v0, sum = 1.0f;
    float acc = h1[(size_t)n * F1 + j];
    int r0 = rowstart[n], r1 = rowstart[n + 1];
    for (int k = r0; k < r1; ++k) {
        int s = csr[k];
        float v = als[s * HEADS + h] + aldn;
        v = v > 0.f ? v : NEG * v;
        float hv = h1[(size_t)s * F1 + j];
        float nm = fmaxf(m, v);
        float sc = __expf(m - nm);
        float w  = __expf(v - nm);
        sum = sum * sc + w;
        acc = acc * sc + w * hv;
        m = nm;
    }
    float val = acc / sum + b1[j];
    hout[(size_t)n * F1 + j] = val > 0.f ? val : (__expf(val) - 1.0f);
}

// ---------------- Layer 2: GEMM (h1 @ W2) + logits ----------------
__global__ __launch_bounds__(256) void node2_kernel(
    const float* __restrict__ h1, const float* __restrict__ W2,
    const float* __restrict__ a_s, const float* __restrict__ a_d,
    float* __restrict__ h2, float* __restrict__ als2, float* __restrict__ ald2)
{
    __shared__ float W2l[F1 * OUTC];   // 8 KB
    for (int i = threadIdx.x; i < F1 * OUTC; i += 256) W2l[i] = W2[i];
    __syncthreads();
    int n = blockIdx.x * blockDim.x + threadIdx.x;
    if (n >= N_NODES) return;

    float o[OUTC];
    #pragma unroll
    for (int c = 0; c < OUTC; ++c) o[c] = 0.f;
    const float4* xr = (const float4*)(h1 + (size_t)n * F1);
    for (int k4 = 0; k4 < 32; ++k4) {
        float4 xv = xr[k4];
        int k = k4 * 4;
        #pragma unroll
        for (int c = 0; c < OUTC; ++c) {
            o[c] += xv.x * W2l[(k + 0) * OUTC + c] + xv.y * W2l[(k + 1) * OUTC + c]
                  + xv.z * W2l[(k + 2) * OUTC + c] + xv.w * W2l[(k + 3) * OUTC + c];
        }
    }
    float4* h2o = (float4*)(h2 + (size_t)n * OUTC);
    #pragma unroll
    for (int c4 = 0; c4 < 4; ++c4) {
        float4 v; v.x = o[c4*4]; v.y = o[c4*4+1]; v.z = o[c4*4+2]; v.w = o[c4*4+3];
        h2o[c4] = v;
    }
    float ps = 0.f, pd = 0.f;
    #pragma unroll
    for (int c = 0; c < OUTC; ++c) { ps += o[c] * a_s[c]; pd += o[c] * a_d[c]; }
    als2[n] = ps; ald2[n] = pd;
}

// ------ Layer 2 fused gather: 16 lanes per node, 16 nodes per block --------
__global__ __launch_bounds__(256) void agg2_kernel(
    const int* __restrict__ rowstart, const int* __restrict__ csr,
    const float* __restrict__ h2, const float* __restrict__ als,
    const float* __restrict__ ald, const float* __restrict__ b2,
    float* __restrict__ out)
{
    int g = threadIdx.x >> 4, c = threadIdx.x & 15;
    int n = blockIdx.x * 16 + g;
    if (n >= N_NODES) return;
    float aldn = ald[n];
    float v0 = als[n] + aldn;
    v0 = v0 > 0.f ? v0 : NEG * v0;
    float m = v0, sum = 1.0f;
    float acc = h2[(size_t)n * OUTC + c];
    int r0 = rowstart[n], r1 = rowstart[n + 1];
    for (int k = r0; k < r1; ++k) {
        int s = csr[k];
        float v = als[s] + aldn;
        v = v > 0.f ? v : NEG * v;
        float hv = h2[(size_t)s * OUTC + c];
        float nm = fmaxf(m, v);
        float sc = __expf(m - nm);
        float w  = __expf(v - nm);
        sum = sum * sc + w;
        acc = acc * sc + w * hv;
        m = nm;
    }
    out[(size_t)n * OUTC + c] = acc / sum + b2[c];
}

extern "C" void kernel_launch(void* const* d_in, const int* in_sizes, int n_in,
                              void* d_out, int out_size, void* d_ws, size_t ws_size,
                              hipStream_t stream)
{
    const float* x   = (const float*)d_in[0];
    const int*   ei  = (const int*)  d_in[1];
    const float* W1  = (const float*)d_in[2];
    const float* as1 = (const float*)d_in[3];
    const float* ad1 = (const float*)d_in[4];
    const float* b1  = (const float*)d_in[5];
    const float* W2  = (const float*)d_in[6];
    const float* as2 = (const float*)d_in[7];
    const float* ad2 = (const float*)d_in[8];
    const float* b2  = (const float*)d_in[9];
    float* out = (float*)d_out;

    float* ws   = (float*)d_ws;
    float* h1   = ws;                                  // N*128
    float* h1b  = h1   + (size_t)N_NODES * F1;         // N*128
    float* als1 = h1b  + (size_t)N_NODES * F1;         // N*8
    float* ald1 = als1 + N_NODES * HEADS;              // N*8
    float* h2f  = ald1 + N_NODES * HEADS;              // N*16
    float* als2 = h2f  + N_NODES * OUTC;               // N
    float* ald2 = als2 + N_NODES;                      // N
    int*   deg  = (int*)(ald2 + N_NODES);              // N
    int*   rowstart = deg + N_NODES;                   // N+1
    int*   cursor   = rowstart + N_NODES + 1;          // N
    int*   part     = cursor + N_NODES;                // N
    int*   bsums    = part + N_NODES;                  // 256
    int*   csr      = bsums + 256;                     // NE

    // ---- CSR build (shared by both layers) ----
    hipMemsetAsync(deg, 0, N_NODES * sizeof(int), stream);
    count_deg<<<(NE + 255) / 256, 256, 0, stream>>>(ei, deg);
    scan_blocks<<<NB_SCAN, 256, 0, stream>>>(deg, part, bsums);
    scan_sums<<<1, 256, 0, stream>>>(bsums);
    scan_finish<<<NB_SCAN, 256, 0, stream>>>(part, bsums, rowstart, cursor);
    scatter_edges<<<(NE + 255) / 256, 256, 0, stream>>>(ei, cursor, csr);

    // ---- layer 1 ----
    node1_kernel<<<512, 256, 0, stream>>>(x, W1, as1, ad1, h1, als1, ald1);
    agg1_kernel<<<N_NODES, 128, 0, stream>>>(rowstart, csr, h1, als1, ald1, b1, h1b);

    // ---- layer 2 ----
    node2_kernel<<<(N_NODES + 255) / 256, 256, 0, stream>>>(h1b, W2, as2, ad2, h2f, als2, ald2);
    agg2_kernel<<<(N_NODES + 15) / 16, 256, 0, stream>>>(rowstart, csr, h2f, als2, ald2, b2, out);
}

// Round 4
// 308.672 us; speedup vs baseline: 23.8119x; 1.1440x over previous
//
#include <hip/hip_runtime.h>
#include <hip/hip_fp16.h>
#include <math.h>

#define N_NODES 50000
#define NE      800000
#define INC     128
#define F1      128     // HEADS*HID
#define HEADS   8
#define HID     16
#define OUTC    16
#define NEG     0.2f
#define NB_SCAN ((N_NODES + 255) / 256)

union H4 { ushort4 u; __half h[4]; };

// ---------------- CSR build (sort edges by dst) ----------------
__global__ void count_deg(const int* __restrict__ ei, int* __restrict__ deg) {
    int e = blockIdx.x * blockDim.x + threadIdx.x;
    if (e < NE) atomicAdd(&deg[ei[NE + e]], 1);
}

__global__ void scan_blocks(const int* __restrict__ deg, int* __restrict__ part,
                            int* __restrict__ bsums) {
    __shared__ int tmp[256];
    int tid = threadIdx.x;
    int i = blockIdx.x * 256 + tid;
    int v = (i < N_NODES) ? deg[i] : 0;
    tmp[tid] = v; __syncthreads();
    for (int off = 1; off < 256; off <<= 1) {
        int t = (tid >= off) ? tmp[tid - off] : 0;
        __syncthreads();
        tmp[tid] += t;
        __syncthreads();
    }
    if (i < N_NODES) part[i] = tmp[tid] - v;          // exclusive
    if (tid == 255) bsums[blockIdx.x] = tmp[255];
}

__global__ void scan_sums(int* __restrict__ bsums) {  // NB_SCAN <= 256
    __shared__ int tmp[256];
    int tid = threadIdx.x;
    int v = (tid < NB_SCAN) ? bsums[tid] : 0;
    tmp[tid] = v; __syncthreads();
    for (int off = 1; off < 256; off <<= 1) {
        int t = (tid >= off) ? tmp[tid - off] : 0;
        __syncthreads();
        tmp[tid] += t;
        __syncthreads();
    }
    if (tid < NB_SCAN) bsums[tid] = tmp[tid] - v;     // exclusive
}

__global__ void scan_finish(const int* __restrict__ part, const int* __restrict__ bsums,
                            int* __restrict__ rowstart, int* __restrict__ cursor) {
    int i = blockIdx.x * 256 + threadIdx.x;
    if (i < N_NODES) {
        int r = part[i] + bsums[blockIdx.x];
        rowstart[i] = r;
        cursor[i]   = r;
    }
    if (i == 0) rowstart[N_NODES] = NE;
}

__global__ void scatter_edges(const int* __restrict__ ei, int* __restrict__ cursor,
                              int* __restrict__ csr) {
    int e = blockIdx.x * blockDim.x + threadIdx.x;
    if (e < NE) {
        int d = ei[NE + e];
        int p = atomicAdd(&cursor[d], 1);
        csr[p] = ei[e];
    }
}

// ---------------- Layer 1: register-blocked GEMM (x @ W1) + logits ----------
// writes hfeat in fp16 (gather side); logits in fp32
__global__ __launch_bounds__(256) void node1_kernel(
    const float* __restrict__ x, const float* __restrict__ W1,
    const float* __restrict__ a_src, const float* __restrict__ a_dst,
    __half* __restrict__ hfeat, float* __restrict__ als, float* __restrict__ ald)
{
    __shared__ float Wl[INC * F1];      // 64 KB
    __shared__ float Xs[32 * INC];      // 16 KB
    int tid = threadIdx.x;
    for (int idx = tid; idx < INC * F1 / 4; idx += 256)
        ((float4*)Wl)[idx] = ((const float4*)W1)[idx];
    int cb  = (tid & 31) * 4;           // column base
    int grp = tid >> 5;                 // 0..7
    float4 as4 = *(const float4*)(a_src + cb);
    float4 ad4 = *(const float4*)(a_dst + cb);

    const int ntiles = (N_NODES + 31) / 32;
    for (int tile = blockIdx.x; tile < ntiles; tile += gridDim.x) {
        int n0 = tile * 32;
        __syncthreads();
        for (int idx = tid; idx < 32 * INC / 4; idx += 256) {
            int row = idx >> 5;
            int n = n0 + row;
            float4 v = (n < N_NODES) ? ((const float4*)(x + (size_t)n * INC))[idx & 31]
                                     : make_float4(0.f, 0.f, 0.f, 0.f);
            ((float4*)Xs)[idx] = v;
        }
        __syncthreads();

        float4 acc[4];
        #pragma unroll
        for (int m = 0; m < 4; ++m) acc[m] = make_float4(0.f, 0.f, 0.f, 0.f);

        #pragma unroll 4
        for (int k4 = 0; k4 < 32; ++k4) {
            int k = k4 * 4;
            float4 w0 = *(const float4*)(Wl + (k + 0) * F1 + cb);
            float4 w1 = *(const float4*)(Wl + (k + 1) * F1 + cb);
            float4 w2 = *(const float4*)(Wl + (k + 2) * F1 + cb);
            float4 w3 = *(const float4*)(Wl + (k + 3) * F1 + cb);
            #pragma unroll
            for (int m = 0; m < 4; ++m) {
                float4 xv = *(const float4*)(Xs + (grp * 4 + m) * INC + k);
                acc[m].x += xv.x * w0.x + xv.y * w1.x + xv.z * w2.x + xv.w * w3.x;
                acc[m].y += xv.x * w0.y + xv.y * w1.y + xv.z * w2.y + xv.w * w3.y;
                acc[m].z += xv.x * w0.z + xv.y * w1.z + xv.z * w2.z + xv.w * w3.z;
                acc[m].w += xv.x * w0.w + xv.y * w1.w + xv.z * w2.w + xv.w * w3.w;
            }
        }

        #pragma unroll
        for (int m = 0; m < 4; ++m) {
            int n = n0 + grp * 4 + m;
            if (n < N_NODES) {
                H4 t;
                t.h[0] = __float2half(acc[m].x); t.h[1] = __float2half(acc[m].y);
                t.h[2] = __float2half(acc[m].z); t.h[3] = __float2half(acc[m].w);
                *(ushort4*)(hfeat + (size_t)n * F1 + cb) = t.u;
                float ps = acc[m].x * as4.x + acc[m].y * as4.y + acc[m].z * as4.z + acc[m].w * as4.w;
                float pd = acc[m].x * ad4.x + acc[m].y * ad4.y + acc[m].z * ad4.z + acc[m].w * ad4.w;
                ps += __shfl_down(ps, 1, 4); ps += __shfl_down(ps, 2, 4);
                pd += __shfl_down(pd, 1, 4); pd += __shfl_down(pd, 2, 4);
                if ((tid & 3) == 0) {
                    int head = (tid & 31) >> 2;
                    als[n * HEADS + head] = ps;
                    ald[n * HEADS + head] = pd;
                }
            }
        }
    }
}

// ------ Layer 1 fused gather: 32 lanes/node, 4 features(fp16)/lane ------
__global__ __launch_bounds__(256) void agg1_kernel(
    const int* __restrict__ rowstart, const int* __restrict__ csr,
    const __half* __restrict__ h1, const float* __restrict__ als,
    const float* __restrict__ ald, const float* __restrict__ b1,
    float* __restrict__ hout)
{
    int tid = threadIdx.x;
    int n = blockIdx.x * 8 + (tid >> 5);      // 8 nodes per 256-block
    int lane = tid & 31;
    int c = lane * 4;                          // feature base
    int head = lane >> 2;
    float aldn = ald[n * HEADS + head];
    float v0 = als[n * HEADS + head] + aldn;
    v0 = v0 > 0.f ? v0 : NEG * v0;
    float m = v0, sum = 1.0f;
    H4 hs; hs.u = *(const ushort4*)(h1 + (size_t)n * F1 + c);
    float a0 = __half2float(hs.h[0]), a1 = __half2float(hs.h[1]);
    float a2 = __half2float(hs.h[2]), a3 = __half2float(hs.h[3]);
    int r0 = rowstart[n], r1 = rowstart[n + 1];
    for (int k = r0; k < r1; ++k) {
        int s = csr[k];
        float v = als[s * HEADS + head] + aldn;
        v = v > 0.f ? v : NEG * v;
        H4 hv; hv.u = *(const ushort4*)(h1 + (size_t)s * F1 + c);
        float nm = fmaxf(m, v);
        float sc = __expf(m - nm);
        float w  = __expf(v - nm);
        sum = sum * sc + w;
        a0 = a0 * sc + w * __half2float(hv.h[0]);
        a1 = a1 * sc + w * __half2float(hv.h[1]);
        a2 = a2 * sc + w * __half2float(hv.h[2]);
        a3 = a3 * sc + w * __half2float(hv.h[3]);
        m = nm;
    }
    float inv = 1.0f / sum;
    float4 bv = *(const float4*)(b1 + c);
    float4 o;
    o.x = a0 * inv + bv.x; o.y = a1 * inv + bv.y;
    o.z = a2 * inv + bv.z; o.w = a3 * inv + bv.w;
    o.x = o.x > 0.f ? o.x : (__expf(o.x) - 1.0f);
    o.y = o.y > 0.f ? o.y : (__expf(o.y) - 1.0f);
    o.z = o.z > 0.f ? o.z : (__expf(o.z) - 1.0f);
    o.w = o.w > 0.f ? o.w : (__expf(o.w) - 1.0f);
    *(float4*)(hout + (size_t)n * F1 + c) = o;
}

// ---------------- Layer 2: GEMM (h1 @ W2) + logits ----------------
__global__ __launch_bounds__(256) void node2_kernel(
    const float* __restrict__ h1, const float* __restrict__ W2,
    const float* __restrict__ a_s, const float* __restrict__ a_d,
    float* __restrict__ h2, float* __restrict__ als2, float* __restrict__ ald2)
{
    __shared__ float W2l[F1 * OUTC];   // 8 KB
    for (int i = threadIdx.x; i < F1 * OUTC; i += 256) W2l[i] = W2[i];
    __syncthreads();
    int n = blockIdx.x * blockDim.x + threadIdx.x;
    if (n >= N_NODES) return;

    float o[OUTC];
    #pragma unroll
    for (int c = 0; c < OUTC; ++c) o[c] = 0.f;
    const float4* xr = (const float4*)(h1 + (size_t)n * F1);
    for (int k4 = 0; k4 < 32; ++k4) {
        float4 xv = xr[k4];
        int k = k4 * 4;
        #pragma unroll
        for (int c = 0; c < OUTC; ++c) {
            o[c] += xv.x * W2l[(k + 0) * OUTC + c] + xv.y * W2l[(k + 1) * OUTC + c]
                  + xv.z * W2l[(k + 2) * OUTC + c] + xv.w * W2l[(k + 3) * OUTC + c];
        }
    }
    float4* h2o = (float4*)(h2 + (size_t)n * OUTC);
    #pragma unroll
    for (int c4 = 0; c4 < 4; ++c4) {
        float4 v; v.x = o[c4*4]; v.y = o[c4*4+1]; v.z = o[c4*4+2]; v.w = o[c4*4+3];
        h2o[c4] = v;
    }
    float ps = 0.f, pd = 0.f;
    #pragma unroll
    for (int c = 0; c < OUTC; ++c) { ps += o[c] * a_s[c]; pd += o[c] * a_d[c]; }
    als2[n] = ps; ald2[n] = pd;
}

// ------ Layer 2 fused gather: 4 lanes/node, float4/lane ------
__global__ __launch_bounds__(256) void agg2_kernel(
    const int* __restrict__ rowstart, const int* __restrict__ csr,
    const float* __restrict__ h2, const float* __restrict__ als,
    const float* __restrict__ ald, const float* __restrict__ b2,
    float* __restrict__ out)
{
    int tid = threadIdx.x;
    int n = blockIdx.x * 64 + (tid >> 2);     // 64 nodes per 256-block
    if (n >= N_NODES) return;
    int c = (tid & 3) * 4;
    float aldn = ald[n];
    float v0 = als[n] + aldn;
    v0 = v0 > 0.f ? v0 : NEG * v0;
    float m = v0, sum = 1.0f;
    float4 acc = *(const float4*)(h2 + (size_t)n * OUTC + c);
    int r0 = rowstart[n], r1 = rowstart[n + 1];
    for (int k = r0; k < r1; ++k) {
        int s = csr[k];
        float v = als[s] + aldn;
        v = v > 0.f ? v : NEG * v;
        float4 hv = *(const float4*)(h2 + (size_t)s * OUTC + c);
        float nm = fmaxf(m, v);
        float sc = __expf(m - nm);
        float w  = __expf(v - nm);
        sum = sum * sc + w;
        acc.x = acc.x * sc + w * hv.x;
        acc.y = acc.y * sc + w * hv.y;
        acc.z = acc.z * sc + w * hv.z;
        acc.w = acc.w * sc + w * hv.w;
        m = nm;
    }
    float inv = 1.0f / sum;
    float4 bv = *(const float4*)(b2 + c);
    float4 o;
    o.x = acc.x * inv + bv.x; o.y = acc.y * inv + bv.y;
    o.z = acc.z * inv + bv.z; o.w = acc.w * inv + bv.w;
    *(float4*)(out + (size_t)n * OUTC + c) = o;
}

extern "C" void kernel_launch(void* const* d_in, const int* in_sizes, int n_in,
                              void* d_out, int out_size, void* d_ws, size_t ws_size,
                              hipStream_t stream)
{
    const float* x   = (const float*)d_in[0];
    const int*   ei  = (const int*)  d_in[1];
    const float* W1  = (const float*)d_in[2];
    const float* as1 = (const float*)d_in[3];
    const float* ad1 = (const float*)d_in[4];
    const float* b1  = (const float*)d_in[5];
    const float* W2  = (const float*)d_in[6];
    const float* as2 = (const float*)d_in[7];
    const float* ad2 = (const float*)d_in[8];
    const float* b2  = (const float*)d_in[9];
    float* out = (float*)d_out;

    // workspace carve-up (byte-based; all offsets 256B-aligned)
    char* wsb = (char*)d_ws;
    __half* h1h = (__half*)wsb;                                 // N*128 fp16 = 12.8 MB
    float* h1b  = (float*)(wsb + (size_t)N_NODES * F1 * 2);     // N*128 f32
    float* als1 = h1b  + (size_t)N_NODES * F1;                  // N*8
    float* ald1 = als1 + N_NODES * HEADS;                       // N*8
    float* h2f  = ald1 + N_NODES * HEADS;                       // N*16
    float* als2 = h2f  + N_NODES * OUTC;                        // N
    float* ald2 = als2 + N_NODES;                               // N
    int*   deg  = (int*)(ald2 + N_NODES);                       // N
    int*   rowstart = deg + N_NODES;                            // N+1
    int*   cursor   = rowstart + N_NODES + 1;                   // N
    int*   part     = cursor + N_NODES;                         // N
    int*   bsums    = part + N_NODES;                           // 256
    int*   csr      = bsums + 256;                              // NE

    // ---- CSR build (shared by both layers) ----
    hipMemsetAsync(deg, 0, N_NODES * sizeof(int), stream);
    count_deg<<<(NE + 255) / 256, 256, 0, stream>>>(ei, deg);
    scan_blocks<<<NB_SCAN, 256, 0, stream>>>(deg, part, bsums);
    scan_sums<<<1, 256, 0, stream>>>(bsums);
    scan_finish<<<NB_SCAN, 256, 0, stream>>>(part, bsums, rowstart, cursor);
    scatter_edges<<<(NE + 255) / 256, 256, 0, stream>>>(ei, cursor, csr);

    // ---- layer 1 ----
    node1_kernel<<<512, 256, 0, stream>>>(x, W1, as1, ad1, h1h, als1, ald1);
    agg1_kernel<<<N_NODES / 8, 256, 0, stream>>>(rowstart, csr, h1h, als1, ald1, b1, h1b);

    // ---- layer 2 ----
    node2_kernel<<<(N_NODES + 255) / 256, 256, 0, stream>>>(h1b, W2, as2, ad2, h2f, als2, ald2);
    agg2_kernel<<<(N_NODES + 63) / 64, 256, 0, stream>>>(rowstart, csr, h2f, als2, ald2, b2, out);
}

// Round 5
// 288.638 us; speedup vs baseline: 25.4647x; 1.0694x over previous
//
#include <hip/hip_runtime.h>
#include <hip/hip_fp16.h>
#include <math.h>

#define N_NODES 50000
#define NE      800000
#define INC     128
#define F1      128     // HEADS*HID
#define HEADS   8
#define HID     16
#define OUTC    16
#define NEG     0.2f
#define NB_SCAN ((N_NODES + 255) / 256)

union H4 { ushort4 u; __half h[4]; };
union H8 { uint4 u; __half h[8]; };

// ---------------- CSR build (sort edges by dst) ----------------
__global__ void count_deg(const int* __restrict__ ei, int* __restrict__ deg) {
    int e = blockIdx.x * blockDim.x + threadIdx.x;
    if (e < NE) atomicAdd(&deg[ei[NE + e]], 1);
}

__global__ void scan_blocks(const int* __restrict__ deg, int* __restrict__ part,
                            int* __restrict__ bsums) {
    __shared__ int tmp[256];
    int tid = threadIdx.x;
    int i = blockIdx.x * 256 + tid;
    int v = (i < N_NODES) ? deg[i] : 0;
    tmp[tid] = v; __syncthreads();
    for (int off = 1; off < 256; off <<= 1) {
        int t = (tid >= off) ? tmp[tid - off] : 0;
        __syncthreads();
        tmp[tid] += t;
        __syncthreads();
    }
    if (i < N_NODES) part[i] = tmp[tid] - v;          // exclusive
    if (tid == 255) bsums[blockIdx.x] = tmp[255];
}

// merged: re-scan bsums in LDS (redundant per block, tiny) + finish
__global__ void scan_finish(const int* __restrict__ part, const int* __restrict__ bsums,
                            int* __restrict__ rowstart, int* __restrict__ cursor) {
    __shared__ int tmp[256];
    __shared__ int excl[256];
    int tid = threadIdx.x;
    int v = (tid < NB_SCAN) ? bsums[tid] : 0;
    tmp[tid] = v; __syncthreads();
    for (int off = 1; off < 256; off <<= 1) {
        int t = (tid >= off) ? tmp[tid - off] : 0;
        __syncthreads();
        tmp[tid] += t;
        __syncthreads();
    }
    excl[tid] = tmp[tid] - v;
    __syncthreads();
    int base = excl[blockIdx.x];
    int i = blockIdx.x * 256 + tid;
    if (i < N_NODES) {
        int r = part[i] + base;
        rowstart[i] = r;
        cursor[i]   = r;
    }
    if (i == 0) rowstart[N_NODES] = NE;
}

__global__ void scatter_edges(const int* __restrict__ ei, int* __restrict__ cursor,
                              int* __restrict__ csr) {
    int e = blockIdx.x * blockDim.x + threadIdx.x;
    if (e < NE) {
        int d = ei[NE + e];
        int p = atomicAdd(&cursor[d], 1);
        csr[p] = ei[e];
    }
}

// ---------------- Layer 1: register-blocked GEMM (x @ W1) + logits ----------
__global__ __launch_bounds__(256) void node1_kernel(
    const float* __restrict__ x, const float* __restrict__ W1,
    const float* __restrict__ a_src, const float* __restrict__ a_dst,
    __half* __restrict__ hfeat, float* __restrict__ als, float* __restrict__ ald)
{
    __shared__ float Wl[INC * F1];      // 64 KB
    __shared__ float Xs[32 * INC];      // 16 KB
    int tid = threadIdx.x;
    for (int idx = tid; idx < INC * F1 / 4; idx += 256)
        ((float4*)Wl)[idx] = ((const float4*)W1)[idx];
    int cb  = (tid & 31) * 4;           // column base
    int grp = tid >> 5;                 // 0..7
    float4 as4 = *(const float4*)(a_src + cb);
    float4 ad4 = *(const float4*)(a_dst + cb);

    const int ntiles = (N_NODES + 31) / 32;
    for (int tile = blockIdx.x; tile < ntiles; tile += gridDim.x) {
        int n0 = tile * 32;
        __syncthreads();
        for (int idx = tid; idx < 32 * INC / 4; idx += 256) {
            int row = idx >> 5;
            int n = n0 + row;
            float4 v = (n < N_NODES) ? ((const float4*)(x + (size_t)n * INC))[idx & 31]
                                     : make_float4(0.f, 0.f, 0.f, 0.f);
            ((float4*)Xs)[idx] = v;
        }
        __syncthreads();

        float4 acc[4];
        #pragma unroll
        for (int m = 0; m < 4; ++m) acc[m] = make_float4(0.f, 0.f, 0.f, 0.f);

        #pragma unroll 4
        for (int k4 = 0; k4 < 32; ++k4) {
            int k = k4 * 4;
            float4 w0 = *(const float4*)(Wl + (k + 0) * F1 + cb);
            float4 w1 = *(const float4*)(Wl + (k + 1) * F1 + cb);
            float4 w2 = *(const float4*)(Wl + (k + 2) * F1 + cb);
            float4 w3 = *(const float4*)(Wl + (k + 3) * F1 + cb);
            #pragma unroll
            for (int m = 0; m < 4; ++m) {
                float4 xv = *(const float4*)(Xs + (grp * 4 + m) * INC + k);
                acc[m].x += xv.x * w0.x + xv.y * w1.x + xv.z * w2.x + xv.w * w3.x;
                acc[m].y += xv.x * w0.y + xv.y * w1.y + xv.z * w2.y + xv.w * w3.y;
                acc[m].z += xv.x * w0.z + xv.y * w1.z + xv.z * w2.z + xv.w * w3.z;
                acc[m].w += xv.x * w0.w + xv.y * w1.w + xv.z * w2.w + xv.w * w3.w;
            }
        }

        #pragma unroll
        for (int m = 0; m < 4; ++m) {
            int n = n0 + grp * 4 + m;
            if (n < N_NODES) {
                H4 t;
                t.h[0] = __float2half(acc[m].x); t.h[1] = __float2half(acc[m].y);
                t.h[2] = __float2half(acc[m].z); t.h[3] = __float2half(acc[m].w);
                *(ushort4*)(hfeat + (size_t)n * F1 + cb) = t.u;
                float ps = acc[m].x * as4.x + acc[m].y * as4.y + acc[m].z * as4.z + acc[m].w * as4.w;
                float pd = acc[m].x * ad4.x + acc[m].y * ad4.y + acc[m].z * ad4.z + acc[m].w * ad4.w;
                ps += __shfl_down(ps, 1, 4); ps += __shfl_down(ps, 2, 4);
                pd += __shfl_down(pd, 1, 4); pd += __shfl_down(pd, 2, 4);
                if ((tid & 3) == 0) {
                    int head = (tid & 31) >> 2;
                    als[n * HEADS + head] = ps;
                    ald[n * HEADS + head] = pd;
                }
            }
        }
    }
}

// ------ Layer 1 gather: 32 lanes/node, 4 fp16 feats/lane, no-max softmax ---
// logits bounded (|v| < ~4), so plain exp is safe; softmax shift-invariant.
__global__ __launch_bounds__(256) void agg1_kernel(
    const int* __restrict__ rowstart, const int* __restrict__ csr,
    const __half* __restrict__ h1, const float* __restrict__ als,
    const float* __restrict__ ald, const float* __restrict__ b1,
    __half* __restrict__ hout)
{
    int tid = threadIdx.x;
    int n = blockIdx.x * 8 + (tid >> 5);
    int lane = tid & 31;
    int c = lane * 4;
    int head = lane >> 2;
    float aldn = ald[n * HEADS + head];
    float v0 = als[n * HEADS + head] + aldn;
    v0 = fmaxf(v0, NEG * v0);
    float w0 = __expf(v0);
    float sum = w0;
    H4 hs; hs.u = *(const ushort4*)(h1 + (size_t)n * F1 + c);
    float a0 = w0 * __half2float(hs.h[0]), a1 = w0 * __half2float(hs.h[1]);
    float a2 = w0 * __half2float(hs.h[2]), a3 = w0 * __half2float(hs.h[3]);
    int r0 = rowstart[n], r1 = rowstart[n + 1];

    // software pipeline: csr 2 ahead, (v, hrow) 1 ahead
    int sB = (r0 + 1 < r1) ? csr[r0 + 1] : 0;
    float vN = 0.f; H4 hN; hN.u = make_ushort4(0, 0, 0, 0);
    if (r0 < r1) {
        int sA = csr[r0];
        float t = als[sA * HEADS + head] + aldn;
        vN = fmaxf(t, NEG * t);
        hN.u = *(const ushort4*)(h1 + (size_t)sA * F1 + c);
    }
    for (int k = r0; k < r1; ++k) {
        float v = vN; H4 hv = hN;
        int sC = (k + 2 < r1) ? csr[k + 2] : 0;
        if (k + 1 < r1) {
            float t = als[sB * HEADS + head] + aldn;
            vN = fmaxf(t, NEG * t);
            hN.u = *(const ushort4*)(h1 + (size_t)sB * F1 + c);
        }
        sB = sC;
        float w = __expf(v);
        sum += w;
        a0 = fmaf(w, __half2float(hv.h[0]), a0);
        a1 = fmaf(w, __half2float(hv.h[1]), a1);
        a2 = fmaf(w, __half2float(hv.h[2]), a2);
        a3 = fmaf(w, __half2float(hv.h[3]), a3);
    }
    float inv = 1.0f / sum;
    float4 bv = *(const float4*)(b1 + c);
    float o0 = a0 * inv + bv.x, o1 = a1 * inv + bv.y;
    float o2 = a2 * inv + bv.z, o3 = a3 * inv + bv.w;
    o0 = o0 > 0.f ? o0 : (__expf(o0) - 1.0f);
    o1 = o1 > 0.f ? o1 : (__expf(o1) - 1.0f);
    o2 = o2 > 0.f ? o2 : (__expf(o2) - 1.0f);
    o3 = o3 > 0.f ? o3 : (__expf(o3) - 1.0f);
    H4 t;
    t.h[0] = __float2half(o0); t.h[1] = __float2half(o1);
    t.h[2] = __float2half(o2); t.h[3] = __float2half(o3);
    *(ushort4*)(hout + (size_t)n * F1 + c) = t.u;
}

// ---------------- Layer 2: GEMM (h1' @ W2) + logits, fp16 in/out ----------
__global__ __launch_bounds__(256) void node2_kernel(
    const __half* __restrict__ h1, const float* __restrict__ W2,
    const float* __restrict__ a_s, const float* __restrict__ a_d,
    __half* __restrict__ h2, float* __restrict__ als2, float* __restrict__ ald2)
{
    __shared__ float W2l[F1 * OUTC];   // 8 KB
    for (int i = threadIdx.x; i < F1 * OUTC; i += 256) W2l[i] = W2[i];
    __syncthreads();
    int n = blockIdx.x * blockDim.x + threadIdx.x;
    if (n >= N_NODES) return;

    float o[OUTC];
    #pragma unroll
    for (int c = 0; c < OUTC; ++c) o[c] = 0.f;
    const uint4* xr = (const uint4*)(h1 + (size_t)n * F1);
    for (int k8 = 0; k8 < 16; ++k8) {
        H8 xv; xv.u = xr[k8];
        int k = k8 * 8;
        #pragma unroll
        for (int j = 0; j < 8; ++j) {
            float xf = __half2float(xv.h[j]);
            #pragma unroll
            for (int c = 0; c < OUTC; ++c)
                o[c] = fmaf(xf, W2l[(k + j) * OUTC + c], o[c]);
        }
    }
    H8 s0, s1;
    #pragma unroll
    for (int j = 0; j < 8; ++j) { s0.h[j] = __float2half(o[j]); s1.h[j] = __float2half(o[8 + j]); }
    uint4* h2o = (uint4*)(h2 + (size_t)n * OUTC);
    h2o[0] = s0.u; h2o[1] = s1.u;
    float ps = 0.f, pd = 0.f;
    #pragma unroll
    for (int c = 0; c < OUTC; ++c) { ps += o[c] * a_s[c]; pd += o[c] * a_d[c]; }
    als2[n] = ps; ald2[n] = pd;
}

// ------ Layer 2 gather: 4 lanes/node, 4 fp16 feats/lane, no-max softmax ----
__global__ __launch_bounds__(256) void agg2_kernel(
    const int* __restrict__ rowstart, const int* __restrict__ csr,
    const __half* __restrict__ h2, const float* __restrict__ als,
    const float* __restrict__ ald, const float* __restrict__ b2,
    float* __restrict__ out)
{
    int tid = threadIdx.x;
    int n = blockIdx.x * 64 + (tid >> 2);
    if (n >= N_NODES) return;
    int c = (tid & 3) * 4;
    float aldn = ald[n];
    float v0 = als[n] + aldn;
    v0 = fmaxf(v0, NEG * v0);
    float w0 = __expf(v0);
    float sum = w0;
    H4 hs; hs.u = *(const ushort4*)(h2 + (size_t)n * OUTC + c);
    float a0 = w0 * __half2float(hs.h[0]), a1 = w0 * __half2float(hs.h[1]);
    float a2 = w0 * __half2float(hs.h[2]), a3 = w0 * __half2float(hs.h[3]);
    int r0 = rowstart[n], r1 = rowstart[n + 1];

    int sB = (r0 + 1 < r1) ? csr[r0 + 1] : 0;
    float vN = 0.f; H4 hN; hN.u = make_ushort4(0, 0, 0, 0);
    if (r0 < r1) {
        int sA = csr[r0];
        float t = als[sA] + aldn;
        vN = fmaxf(t, NEG * t);
        hN.u = *(const ushort4*)(h2 + (size_t)sA * OUTC + c);
    }
    for (int k = r0; k < r1; ++k) {
        float v = vN; H4 hv = hN;
        int sC = (k + 2 < r1) ? csr[k + 2] : 0;
        if (k + 1 < r1) {
            float t = als[sB] + aldn;
            vN = fmaxf(t, NEG * t);
            hN.u = *(const ushort4*)(h2 + (size_t)sB * OUTC + c);
        }
        sB = sC;
        float w = __expf(v);
        sum += w;
        a0 = fmaf(w, __half2float(hv.h[0]), a0);
        a1 = fmaf(w, __half2float(hv.h[1]), a1);
        a2 = fmaf(w, __half2float(hv.h[2]), a2);
        a3 = fmaf(w, __half2float(hv.h[3]), a3);
    }
    float inv = 1.0f / sum;
    float4 bv = *(const float4*)(b2 + c);
    float4 o;
    o.x = a0 * inv + bv.x; o.y = a1 * inv + bv.y;
    o.z = a2 * inv + bv.z; o.w = a3 * inv + bv.w;
    *(float4*)(out + (size_t)n * OUTC + c) = o;
}

extern "C" void kernel_launch(void* const* d_in, const int* in_sizes, int n_in,
                              void* d_out, int out_size, void* d_ws, size_t ws_size,
                              hipStream_t stream)
{
    const float* x   = (const float*)d_in[0];
    const int*   ei  = (const int*)  d_in[1];
    const float* W1  = (const float*)d_in[2];
    const float* as1 = (const float*)d_in[3];
    const float* ad1 = (const float*)d_in[4];
    const float* b1  = (const float*)d_in[5];
    const float* W2  = (const float*)d_in[6];
    const float* as2 = (const float*)d_in[7];
    const float* ad2 = (const float*)d_in[8];
    const float* b2  = (const float*)d_in[9];
    float* out = (float*)d_out;

    // workspace carve-up (byte offsets; all 16B-aligned)
    char* wsb = (char*)d_ws;
    const size_t SZ_H1 = (size_t)N_NODES * F1 * sizeof(__half);   // 12.8 MB
    __half* h1h = (__half*)wsb;                                   // fp16 pre-softmax h1
    __half* h1b = (__half*)(wsb + SZ_H1);                         // fp16 post-ELU h1'
    float*  als1 = (float*)(wsb + 2 * SZ_H1);                     // N*8
    float*  ald1 = als1 + N_NODES * HEADS;                        // N*8
    __half* h2f  = (__half*)(ald1 + N_NODES * HEADS);             // N*16 fp16
    float*  als2 = (float*)(h2f + (size_t)N_NODES * OUTC);        // N
    float*  ald2 = als2 + N_NODES;                                // N
    int*    deg  = (int*)(ald2 + N_NODES);                        // N
    int*    rowstart = deg + N_NODES;                             // N+1
    int*    cursor   = rowstart + N_NODES + 1;                    // N
    int*    part     = cursor + N_NODES;                          // N
    int*    bsums    = part + N_NODES;                            // 256
    int*    csr      = bsums + 256;                               // NE

    // ---- CSR build (shared by both layers) ----
    hipMemsetAsync(deg, 0, N_NODES * sizeof(int), stream);
    count_deg<<<(NE + 255) / 256, 256, 0, stream>>>(ei, deg);
    scan_blocks<<<NB_SCAN, 256, 0, stream>>>(deg, part, bsums);
    scan_finish<<<NB_SCAN, 256, 0, stream>>>(part, bsums, rowstart, cursor);
    scatter_edges<<<(NE + 255) / 256, 256, 0, stream>>>(ei, cursor, csr);

    // ---- layer 1 ----
    node1_kernel<<<512, 256, 0, stream>>>(x, W1, as1, ad1, h1h, als1, ald1);
    agg1_kernel<<<N_NODES / 8, 256, 0, stream>>>(rowstart, csr, h1h, als1, ald1, b1, h1b);

    // ---- layer 2 ----
    node2_kernel<<<(N_NODES + 255) / 256, 256, 0, stream>>>(h1b, W2, as2, ad2, h2f, als2, ald2);
    agg2_kernel<<<(N_NODES + 63) / 64, 256, 0, stream>>>(rowstart, csr, h2f, als2, ald2, b2, out);
}

// Round 6
// 286.186 us; speedup vs baseline: 25.6829x; 1.0086x over previous
//
#include <hip/hip_runtime.h>
#include <hip/hip_fp16.h>
#include <math.h>

#define N_NODES 50000
#define NE      800000
#define INC     128
#define F1      128     // HEADS*HID
#define HEADS   8
#define HID     16
#define OUTC    16
#define NEG     0.2f
#define NB_SCAN ((N_NODES + 255) / 256)

union H4 { ushort4 u; __half h[4]; };
union H8 { uint4 u; __half h[8]; };

typedef _Float16 f16x8 __attribute__((ext_vector_type(8)));
typedef float    f32x4 __attribute__((ext_vector_type(4)));

// ---------------- CSR build (sort edges by dst) ----------------
__global__ void count_deg(const int* __restrict__ ei, int* __restrict__ deg) {
    int e = blockIdx.x * blockDim.x + threadIdx.x;
    if (e < NE) atomicAdd(&deg[ei[NE + e]], 1);
}

__global__ void scan_blocks(const int* __restrict__ deg, int* __restrict__ part,
                            int* __restrict__ bsums) {
    __shared__ int tmp[256];
    int tid = threadIdx.x;
    int i = blockIdx.x * 256 + tid;
    int v = (i < N_NODES) ? deg[i] : 0;
    tmp[tid] = v; __syncthreads();
    for (int off = 1; off < 256; off <<= 1) {
        int t = (tid >= off) ? tmp[tid - off] : 0;
        __syncthreads();
        tmp[tid] += t;
        __syncthreads();
    }
    if (i < N_NODES) part[i] = tmp[tid] - v;          // exclusive
    if (tid == 255) bsums[blockIdx.x] = tmp[255];
}

// merged: re-scan bsums in LDS (redundant per block, tiny) + finish
__global__ void scan_finish(const int* __restrict__ part, const int* __restrict__ bsums,
                            int* __restrict__ rowstart, int* __restrict__ cursor) {
    __shared__ int tmp[256];
    __shared__ int excl[256];
    int tid = threadIdx.x;
    int v = (tid < NB_SCAN) ? bsums[tid] : 0;
    tmp[tid] = v; __syncthreads();
    for (int off = 1; off < 256; off <<= 1) {
        int t = (tid >= off) ? tmp[tid - off] : 0;
        __syncthreads();
        tmp[tid] += t;
        __syncthreads();
    }
    excl[tid] = tmp[tid] - v;
    __syncthreads();
    int base = excl[blockIdx.x];
    int i = blockIdx.x * 256 + tid;
    if (i < N_NODES) {
        int r = part[i] + base;
        rowstart[i] = r;
        cursor[i]   = r;
    }
    if (i == 0) rowstart[N_NODES] = NE;
}

__global__ void scatter_edges(const int* __restrict__ ei, int* __restrict__ cursor,
                              int* __restrict__ csr) {
    int e = blockIdx.x * blockDim.x + threadIdx.x;
    if (e < NE) {
        int d = ei[NE + e];
        int p = atomicAdd(&cursor[d], 1);
        csr[p] = ei[e];
    }
}

// ---------------- Layer 1: MFMA GEMM (x @ W1), fp16 in, f32 acc ------------
// block = 256 (4 waves): 64 nodes x 128 cols per block.
// wave w: cols w*32..w*32+31 (2 n-tiles), 4 m-tiles of 16 nodes.
// LDS: Xh[64][136] fp16 (pad 8 halves kills the 256B-stride bank conflict),
//      Wt[128][136] fp16 = W1 transposed so B frags are contiguous b128 reads.
__global__ __launch_bounds__(256) void node1_kernel(
    const float* __restrict__ x, const float* __restrict__ W1,
    const float* __restrict__ a_src, const float* __restrict__ a_dst,
    __half* __restrict__ hfeat, float* __restrict__ als, float* __restrict__ ald)
{
    __shared__ _Float16 Xh[64 * 136];    // 17.4 KB
    __shared__ _Float16 Wt[128 * 136];   // 34.8 KB
    int tid = threadIdx.x;
    int n0 = blockIdx.x * 64;

    // stage W1 transposed: Wt[n][k] = W1[k][n]
    for (int idx = tid; idx < INC * F1 / 4; idx += 256) {
        int k = idx >> 5, n4 = (idx & 31) * 4;
        float4 w = ((const float4*)W1)[idx];
        Wt[(n4 + 0) * 136 + k] = (_Float16)w.x;
        Wt[(n4 + 1) * 136 + k] = (_Float16)w.y;
        Wt[(n4 + 2) * 136 + k] = (_Float16)w.z;
        Wt[(n4 + 3) * 136 + k] = (_Float16)w.w;
    }
    // stage X tile as fp16
    for (int idx = tid; idx < 64 * 32; idx += 256) {
        int m = idx >> 5, f4 = idx & 31;
        int n = n0 + m;
        float4 v = (n < N_NODES) ? ((const float4*)(x + (size_t)n * INC))[f4]
                                 : make_float4(0.f, 0.f, 0.f, 0.f);
        union { unsigned long long u; _Float16 h[4]; } p;
        p.h[0] = (_Float16)v.x; p.h[1] = (_Float16)v.y;
        p.h[2] = (_Float16)v.z; p.h[3] = (_Float16)v.w;
        *(unsigned long long*)(&Xh[m * 136 + f4 * 4]) = p.u;
    }
    __syncthreads();

    int wave = tid >> 6, lane = tid & 63;
    int colL = lane & 15, q = lane >> 4;      // q = quad, k-offset q*8
    int nb = wave * 32;

    f32x4 acc[4][2];
    #pragma unroll
    for (int mt = 0; mt < 4; ++mt)
        #pragma unroll
        for (int nt = 0; nt < 2; ++nt)
            acc[mt][nt] = (f32x4){0.f, 0.f, 0.f, 0.f};

    #pragma unroll
    for (int kb = 0; kb < 4; ++kb) {
        int ko = kb * 32 + q * 8;
        f16x8 b0 = *(const f16x8*)(&Wt[(nb +  0 + colL) * 136 + ko]);
        f16x8 b1 = *(const f16x8*)(&Wt[(nb + 16 + colL) * 136 + ko]);
        #pragma unroll
        for (int mt = 0; mt < 4; ++mt) {
            f16x8 a = *(const f16x8*)(&Xh[(mt * 16 + colL) * 136 + ko]);
            acc[mt][0] = __builtin_amdgcn_mfma_f32_16x16x32_f16(a, b0, acc[mt][0], 0, 0, 0);
            acc[mt][1] = __builtin_amdgcn_mfma_f32_16x16x32_f16(a, b1, acc[mt][1], 0, 0, 0);
        }
    }

    // epilogue: store h (fp16) + per-head logits (head == n-tile)
    #pragma unroll
    for (int nt = 0; nt < 2; ++nt) {
        int col = nb + nt * 16 + colL;
        int head = (nb >> 4) + nt;
        float asc = a_src[col], adc = a_dst[col];
        #pragma unroll
        for (int mt = 0; mt < 4; ++mt) {
            f32x4 d = acc[mt][nt];
            #pragma unroll
            for (int r = 0; r < 4; ++r) {
                int node = n0 + mt * 16 + q * 4 + r;
                float dv = d[r];
                if (node < N_NODES) hfeat[(size_t)node * F1 + col] = __float2half(dv);
                float ps = dv * asc, pd = dv * adc;
                ps += __shfl_xor(ps, 1, 16); pd += __shfl_xor(pd, 1, 16);
                ps += __shfl_xor(ps, 2, 16); pd += __shfl_xor(pd, 2, 16);
                ps += __shfl_xor(ps, 4, 16); pd += __shfl_xor(pd, 4, 16);
                ps += __shfl_xor(ps, 8, 16); pd += __shfl_xor(pd, 8, 16);
                if (colL == 0 && node < N_NODES) {
                    als[node * HEADS + head] = ps;
                    ald[node * HEADS + head] = pd;
                }
            }
        }
    }
}

// ------ Layer 1 gather: 16 lanes/node, 8 fp16 feats/lane, no-max softmax ---
__global__ __launch_bounds__(256) void agg1_kernel(
    const int* __restrict__ rowstart, const int* __restrict__ csr,
    const __half* __restrict__ h1, const float* __restrict__ als,
    const float* __restrict__ ald, const float* __restrict__ b1,
    __half* __restrict__ hout)
{
    int tid = threadIdx.x;
    int n = blockIdx.x * 16 + (tid >> 4);
    int lane = tid & 15;
    int c = lane * 8;
    int head = lane >> 1;
    float aldn = ald[n * HEADS + head];
    float v0 = als[n * HEADS + head] + aldn;
    v0 = fmaxf(v0, NEG * v0);
    float w0 = __expf(v0);
    float sum = w0;
    float a[8];
    {
        H8 hs; hs.u = *(const uint4*)(h1 + (size_t)n * F1 + c);
        #pragma unroll
        for (int i = 0; i < 8; ++i) a[i] = w0 * __half2float(hs.h[i]);
    }
    int r0 = rowstart[n], r1 = rowstart[n + 1];

    // software pipeline: csr 2 ahead, (v, hrow) 1 ahead
    int sB = (r0 + 1 < r1) ? csr[r0 + 1] : 0;
    float vN = 0.f; H8 hN; hN.u = make_uint4(0, 0, 0, 0);
    if (r0 < r1) {
        int sA = csr[r0];
        float t = als[sA * HEADS + head] + aldn;
        vN = fmaxf(t, NEG * t);
        hN.u = *(const uint4*)(h1 + (size_t)sA * F1 + c);
    }
    for (int k = r0; k < r1; ++k) {
        float v = vN; H8 hv = hN;
        int sC = (k + 2 < r1) ? csr[k + 2] : 0;
        if (k + 1 < r1) {
            float t = als[sB * HEADS + head] + aldn;
            vN = fmaxf(t, NEG * t);
            hN.u = *(const uint4*)(h1 + (size_t)sB * F1 + c);
        }
        sB = sC;
        float w = __expf(v);
        sum += w;
        #pragma unroll
        for (int i = 0; i < 8; ++i) a[i] = fmaf(w, __half2float(hv.h[i]), a[i]);
    }
    float inv = 1.0f / sum;
    H8 t;
    #pragma unroll
    for (int i = 0; i < 8; ++i) {
        float o = a[i] * inv + b1[c + i];
        o = o > 0.f ? o : (__expf(o) - 1.0f);
        t.h[i] = __float2half(o);
    }
    *(uint4*)(hout + (size_t)n * F1 + c) = t.u;
}

// ---------------- Layer 2: GEMM (h1' @ W2) + logits, fp16 in/out ----------
__global__ __launch_bounds__(256) void node2_kernel(
    const __half* __restrict__ h1, const float* __restrict__ W2,
    const float* __restrict__ a_s, const float* __restrict__ a_d,
    __half* __restrict__ h2, float* __restrict__ als2, float* __restrict__ ald2)
{
    __shared__ float W2l[F1 * OUTC];   // 8 KB
    for (int i = threadIdx.x; i < F1 * OUTC; i += 256) W2l[i] = W2[i];
    __syncthreads();
    int n = blockIdx.x * blockDim.x + threadIdx.x;
    if (n >= N_NODES) return;

    float o[OUTC];
    #pragma unroll
    for (int c = 0; c < OUTC; ++c) o[c] = 0.f;
    const uint4* xr = (const uint4*)(h1 + (size_t)n * F1);
    for (int k8 = 0; k8 < 16; ++k8) {
        H8 xv; xv.u = xr[k8];
        int k = k8 * 8;
        #pragma unroll
        for (int j = 0; j < 8; ++j) {
            float xf = __half2float(xv.h[j]);
            #pragma unroll
            for (int c = 0; c < OUTC; ++c)
                o[c] = fmaf(xf, W2l[(k + j) * OUTC + c], o[c]);
        }
    }
    H8 s0, s1;
    #pragma unroll
    for (int j = 0; j < 8; ++j) { s0.h[j] = __float2half(o[j]); s1.h[j] = __float2half(o[8 + j]); }
    uint4* h2o = (uint4*)(h2 + (size_t)n * OUTC);
    h2o[0] = s0.u; h2o[1] = s1.u;
    float ps = 0.f, pd = 0.f;
    #pragma unroll
    for (int c = 0; c < OUTC; ++c) { ps += o[c] * a_s[c]; pd += o[c] * a_d[c]; }
    als2[n] = ps; ald2[n] = pd;
}

// ------ Layer 2 gather: 4 lanes/node, 4 fp16 feats/lane, no-max softmax ----
__global__ __launch_bounds__(256) void agg2_kernel(
    const int* __restrict__ rowstart, const int* __restrict__ csr,
    const __half* __restrict__ h2, const float* __restrict__ als,
    const float* __restrict__ ald, const float* __restrict__ b2,
    float* __restrict__ out)
{
    int tid = threadIdx.x;
    int n = blockIdx.x * 64 + (tid >> 2);
    if (n >= N_NODES) return;
    int c = (tid & 3) * 4;
    float aldn = ald[n];
    float v0 = als[n] + aldn;
    v0 = fmaxf(v0, NEG * v0);
    float w0 = __expf(v0);
    float sum = w0;
    H4 hs; hs.u = *(const ushort4*)(h2 + (size_t)n * OUTC + c);
    float a0 = w0 * __half2float(hs.h[0]), a1 = w0 * __half2float(hs.h[1]);
    float a2 = w0 * __half2float(hs.h[2]), a3 = w0 * __half2float(hs.h[3]);
    int r0 = rowstart[n], r1 = rowstart[n + 1];

    int sB = (r0 + 1 < r1) ? csr[r0 + 1] : 0;
    float vN = 0.f; H4 hN; hN.u = make_ushort4(0, 0, 0, 0);
    if (r0 < r1) {
        int sA = csr[r0];
        float t = als[sA] + aldn;
        vN = fmaxf(t, NEG * t);
        hN.u = *(const ushort4*)(h2 + (size_t)sA * OUTC + c);
    }
    for (int k = r0; k < r1; ++k) {
        float v = vN; H4 hv = hN;
        int sC = (k + 2 < r1) ? csr[k + 2] : 0;
        if (k + 1 < r1) {
            float t = als[sB] + aldn;
            vN = fmaxf(t, NEG * t);
            hN.u = *(const ushort4*)(h2 + (size_t)sB * OUTC + c);
        }
        sB = sC;
        float w = __expf(v);
        sum += w;
        a0 = fmaf(w, __half2float(hv.h[0]), a0);
        a1 = fmaf(w, __half2float(hv.h[1]), a1);
        a2 = fmaf(w, __half2float(hv.h[2]), a2);
        a3 = fmaf(w, __half2float(hv.h[3]), a3);
    }
    float inv = 1.0f / sum;
    float4 bv = *(const float4*)(b2 + c);
    float4 o;
    o.x = a0 * inv + bv.x; o.y = a1 * inv + bv.y;
    o.z = a2 * inv + bv.z; o.w = a3 * inv + bv.w;
    *(float4*)(out + (size_t)n * OUTC + c) = o;
}

extern "C" void kernel_launch(void* const* d_in, const int* in_sizes, int n_in,
                              void* d_out, int out_size, void* d_ws, size_t ws_size,
                              hipStream_t stream)
{
    const float* x   = (const float*)d_in[0];
    const int*   ei  = (const int*)  d_in[1];
    const float* W1  = (const float*)d_in[2];
    const float* as1 = (const float*)d_in[3];
    const float* ad1 = (const float*)d_in[4];
    const float* b1  = (const float*)d_in[5];
    const float* W2  = (const float*)d_in[6];
    const float* as2 = (const float*)d_in[7];
    const float* ad2 = (const float*)d_in[8];
    const float* b2  = (const float*)d_in[9];
    float* out = (float*)d_out;

    // workspace carve-up (byte offsets; all 16B-aligned)
    char* wsb = (char*)d_ws;
    const size_t SZ_H1 = (size_t)N_NODES * F1 * sizeof(__half);   // 12.8 MB
    __half* h1h = (__half*)wsb;                                   // fp16 pre-softmax h1
    __half* h1b = (__half*)(wsb + SZ_H1);                         // fp16 post-ELU h1'
    float*  als1 = (float*)(wsb + 2 * SZ_H1);                     // N*8
    float*  ald1 = als1 + N_NODES * HEADS;                        // N*8
    __half* h2f  = (__half*)(ald1 + N_NODES * HEADS);             // N*16 fp16
    float*  als2 = (float*)(h2f + (size_t)N_NODES * OUTC);        // N
    float*  ald2 = als2 + N_NODES;                                // N
    int*    deg  = (int*)(ald2 + N_NODES);                        // N
    int*    rowstart = deg + N_NODES;                             // N+1
    int*    cursor   = rowstart + N_NODES + 1;                    // N
    int*    part     = cursor + N_NODES;                          // N
    int*    bsums    = part + N_NODES;                            // 256
    int*    csr      = bsums + 256;                               // NE

    // ---- CSR build (shared by both layers) ----
    hipMemsetAsync(deg, 0, N_NODES * sizeof(int), stream);
    count_deg<<<(NE + 255) / 256, 256, 0, stream>>>(ei, deg);
    scan_blocks<<<NB_SCAN, 256, 0, stream>>>(deg, part, bsums);
    scan_finish<<<NB_SCAN, 256, 0, stream>>>(part, bsums, rowstart, cursor);
    scatter_edges<<<(NE + 255) / 256, 256, 0, stream>>>(ei, cursor, csr);

    // ---- layer 1 ----
    node1_kernel<<<(N_NODES + 63) / 64, 256, 0, stream>>>(x, W1, as1, ad1, h1h, als1, ald1);
    agg1_kernel<<<N_NODES / 16, 256, 0, stream>>>(rowstart, csr, h1h, als1, ald1, b1, h1b);

    // ---- layer 2 ----
    node2_kernel<<<(N_NODES + 255) / 256, 256, 0, stream>>>(h1b, W2, as2, ad2, h2f, als2, ald2);
    agg2_kernel<<<(N_NODES + 63) / 64, 256, 0, stream>>>(rowstart, csr, h2f, als2, ald2, b2, out);
}

// Round 7
// 237.519 us; speedup vs baseline: 30.9452x; 1.2049x over previous
//
#include <hip/hip_runtime.h>
#include <hip/hip_fp16.h>
#include <math.h>

#define N_NODES 50000
#define NE      800000
#define INC     128
#define F1      128     // HEADS*HID
#define HEADS   8
#define HID     16
#define OUTC    16
#define NEG     0.2f
#define NBKT    196      // (N_NODES+255)>>8
#define NPART   256      // partition blocks

union H4 { ushort4 u; __half h[4]; };
union H8 { uint4 u; __half h[8]; };

typedef _Float16 f16x8 __attribute__((ext_vector_type(8)));
typedef float    f32x4 __attribute__((ext_vector_type(4)));

// ============ CSR build: two-level counting sort (locality-friendly) ========
// cnt layout: [bucket][block]  (bucket-major so a flat scan = final edge order)

__global__ __launch_bounds__(256) void part_hist(const int* __restrict__ ei,
                                                 int* __restrict__ cnt) {
    __shared__ int h[NBKT];
    int tid = threadIdx.x;
    for (int i = tid; i < NBKT; i += 256) h[i] = 0;
    __syncthreads();
    for (int e = blockIdx.x * 256 + tid; e < NE; e += NPART * 256)
        atomicAdd(&h[ei[NE + e] >> 8], 1);
    __syncthreads();
    for (int i = tid; i < NBKT; i += 256) cnt[i * NPART + blockIdx.x] = h[i];
}

__global__ __launch_bounds__(1024) void scan50k(int* __restrict__ cnt) {
    // in-place exclusive scan of NBKT*NPART = 50176 ints, single block
    __shared__ int part[1024];
    const int TOT = NBKT * NPART;
    const int PER = (TOT + 1023) / 1024;      // 49
    int tid = threadIdx.x;
    int base = tid * PER;
    int s = 0;
    for (int i = 0; i < PER; ++i) {
        int idx = base + i;
        if (idx < TOT) s += cnt[idx];
    }
    part[tid] = s; __syncthreads();
    for (int off = 1; off < 1024; off <<= 1) {
        int t = (tid >= off) ? part[tid - off] : 0;
        __syncthreads();
        part[tid] += t;
        __syncthreads();
    }
    int run = part[tid] - s;                  // exclusive base for this chunk
    for (int i = 0; i < PER; ++i) {
        int idx = base + i;
        if (idx < TOT) { int v = cnt[idx]; cnt[idx] = run; run += v; }
    }
}

__global__ __launch_bounds__(256) void part_scatter(const int* __restrict__ ei,
                                                    const int* __restrict__ cnt,
                                                    int2* __restrict__ tmp) {
    __shared__ int cur[NBKT];
    int tid = threadIdx.x;
    for (int i = tid; i < NBKT; i += 256) cur[i] = cnt[i * NPART + blockIdx.x];
    __syncthreads();
    for (int e = blockIdx.x * 256 + tid; e < NE; e += NPART * 256) {
        int s = ei[e], d = ei[NE + e];
        int p = atomicAdd(&cur[d >> 8], 1);
        tmp[p] = make_int2(s, d);             // contiguous per-(block,bucket) runs
    }
}

// one block per bucket: counting-sort by dst&255, emit rowstart + csr
__global__ __launch_bounds__(256) void bucket_sort(const int2* __restrict__ tmp,
                                                   const int* __restrict__ cnt,
                                                   int* __restrict__ rowstart,
                                                   int* __restrict__ csr) {
    __shared__ int h[256];
    int b = blockIdx.x, tid = threadIdx.x;
    int base = cnt[b * NPART];
    int end  = (b == NBKT - 1) ? NE : cnt[(b + 1) * NPART];
    h[tid] = 0; __syncthreads();
    for (int i = base + tid; i < end; i += 256)
        atomicAdd(&h[tmp[i].y & 255], 1);
    __syncthreads();
    int v = h[tid];
    for (int off = 1; off < 256; off <<= 1) {       // inclusive scan
        int t = (tid >= off) ? h[tid - off] : 0;
        __syncthreads();
        h[tid] += t;
        __syncthreads();
    }
    int excl = h[tid] - v;
    int n = (b << 8) + tid;
    if (n <= N_NODES) rowstart[n] = base + excl;    // n==N_NODES -> base+bcnt == NE
    __syncthreads();
    h[tid] = excl;                                   // reuse as cursor
    __syncthreads();
    for (int i = base + tid; i < end; i += 256) {
        int2 e = tmp[i];
        int p = base + atomicAdd(&h[e.y & 255], 1);
        csr[p] = e.x;                                // block-private ~16KB region
    }
}

// ---------------- Layer 1: MFMA GEMM (x @ W1), fp16 in, f32 acc ------------
__global__ __launch_bounds__(256) void node1_kernel(
    const float* __restrict__ x, const float* __restrict__ W1,
    const float* __restrict__ a_src, const float* __restrict__ a_dst,
    __half* __restrict__ hfeat, float* __restrict__ als, float* __restrict__ ald)
{
    __shared__ _Float16 Xh[64 * 136];    // 17.4 KB
    __shared__ _Float16 Wt[128 * 136];   // 34.8 KB
    int tid = threadIdx.x;
    int n0 = blockIdx.x * 64;

    for (int idx = tid; idx < INC * F1 / 4; idx += 256) {
        int k = idx >> 5, n4 = (idx & 31) * 4;
        float4 w = ((const float4*)W1)[idx];
        Wt[(n4 + 0) * 136 + k] = (_Float16)w.x;
        Wt[(n4 + 1) * 136 + k] = (_Float16)w.y;
        Wt[(n4 + 2) * 136 + k] = (_Float16)w.z;
        Wt[(n4 + 3) * 136 + k] = (_Float16)w.w;
    }
    for (int idx = tid; idx < 64 * 32; idx += 256) {
        int m = idx >> 5, f4 = idx & 31;
        int n = n0 + m;
        float4 v = (n < N_NODES) ? ((const float4*)(x + (size_t)n * INC))[f4]
                                 : make_float4(0.f, 0.f, 0.f, 0.f);
        union { unsigned long long u; _Float16 h[4]; } p;
        p.h[0] = (_Float16)v.x; p.h[1] = (_Float16)v.y;
        p.h[2] = (_Float16)v.z; p.h[3] = (_Float16)v.w;
        *(unsigned long long*)(&Xh[m * 136 + f4 * 4]) = p.u;
    }
    __syncthreads();

    int wave = tid >> 6, lane = tid & 63;
    int colL = lane & 15, q = lane >> 4;
    int nb = wave * 32;

    f32x4 acc[4][2];
    #pragma unroll
    for (int mt = 0; mt < 4; ++mt)
        #pragma unroll
        for (int nt = 0; nt < 2; ++nt)
            acc[mt][nt] = (f32x4){0.f, 0.f, 0.f, 0.f};

    #pragma unroll
    for (int kb = 0; kb < 4; ++kb) {
        int ko = kb * 32 + q * 8;
        f16x8 b0 = *(const f16x8*)(&Wt[(nb +  0 + colL) * 136 + ko]);
        f16x8 b1 = *(const f16x8*)(&Wt[(nb + 16 + colL) * 136 + ko]);
        #pragma unroll
        for (int mt = 0; mt < 4; ++mt) {
            f16x8 a = *(const f16x8*)(&Xh[(mt * 16 + colL) * 136 + ko]);
            acc[mt][0] = __builtin_amdgcn_mfma_f32_16x16x32_f16(a, b0, acc[mt][0], 0, 0, 0);
            acc[mt][1] = __builtin_amdgcn_mfma_f32_16x16x32_f16(a, b1, acc[mt][1], 0, 0, 0);
        }
    }

    #pragma unroll
    for (int nt = 0; nt < 2; ++nt) {
        int col = nb + nt * 16 + colL;
        int head = (nb >> 4) + nt;
        float asc = a_src[col], adc = a_dst[col];
        #pragma unroll
        for (int mt = 0; mt < 4; ++mt) {
            f32x4 d = acc[mt][nt];
            #pragma unroll
            for (int r = 0; r < 4; ++r) {
                int node = n0 + mt * 16 + q * 4 + r;
                float dv = d[r];
                if (node < N_NODES) hfeat[(size_t)node * F1 + col] = __float2half(dv);
                float ps = dv * asc, pd = dv * adc;
                ps += __shfl_xor(ps, 1, 16); pd += __shfl_xor(pd, 1, 16);
                ps += __shfl_xor(ps, 2, 16); pd += __shfl_xor(pd, 2, 16);
                ps += __shfl_xor(ps, 4, 16); pd += __shfl_xor(pd, 4, 16);
                ps += __shfl_xor(ps, 8, 16); pd += __shfl_xor(pd, 8, 16);
                if (colL == 0 && node < N_NODES) {
                    als[node * HEADS + head] = ps;
                    ald[node * HEADS + head] = pd;
                }
            }
        }
    }
}

// ------ Layer 1 gather: 16 lanes/node, 8 fp16 feats/lane, no-max softmax ---
__global__ __launch_bounds__(256) void agg1_kernel(
    const int* __restrict__ rowstart, const int* __restrict__ csr,
    const __half* __restrict__ h1, const float* __restrict__ als,
    const float* __restrict__ ald, const float* __restrict__ b1,
    __half* __restrict__ hout)
{
    int tid = threadIdx.x;
    int n = blockIdx.x * 16 + (tid >> 4);
    int lane = tid & 15;
    int c = lane * 8;
    int head = lane >> 1;
    float aldn = ald[n * HEADS + head];
    float v0 = als[n * HEADS + head] + aldn;
    v0 = fmaxf(v0, NEG * v0);
    float w0 = __expf(v0);
    float sum = w0;
    float a[8];
    {
        H8 hs; hs.u = *(const uint4*)(h1 + (size_t)n * F1 + c);
        #pragma unroll
        for (int i = 0; i < 8; ++i) a[i] = w0 * __half2float(hs.h[i]);
    }
    int r0 = rowstart[n], r1 = rowstart[n + 1];

    int sB = (r0 + 1 < r1) ? csr[r0 + 1] : 0;
    float vN = 0.f; H8 hN; hN.u = make_uint4(0, 0, 0, 0);
    if (r0 < r1) {
        int sA = csr[r0];
        float t = als[sA * HEADS + head] + aldn;
        vN = fmaxf(t, NEG * t);
        hN.u = *(const uint4*)(h1 + (size_t)sA * F1 + c);
    }
    for (int k = r0; k < r1; ++k) {
        float v = vN; H8 hv = hN;
        int sC = (k + 2 < r1) ? csr[k + 2] : 0;
        if (k + 1 < r1) {
            float t = als[sB * HEADS + head] + aldn;
            vN = fmaxf(t, NEG * t);
            hN.u = *(const uint4*)(h1 + (size_t)sB * F1 + c);
        }
        sB = sC;
        float w = __expf(v);
        sum += w;
        #pragma unroll
        for (int i = 0; i < 8; ++i) a[i] = fmaf(w, __half2float(hv.h[i]), a[i]);
    }
    float inv = 1.0f / sum;
    H8 t;
    #pragma unroll
    for (int i = 0; i < 8; ++i) {
        float o = a[i] * inv + b1[c + i];
        o = o > 0.f ? o : (__expf(o) - 1.0f);
        t.h[i] = __float2half(o);
    }
    *(uint4*)(hout + (size_t)n * F1 + c) = t.u;
}

// ---------------- Layer 2: GEMM (h1' @ W2) + logits, fp16 in/out ----------
__global__ __launch_bounds__(256) void node2_kernel(
    const __half* __restrict__ h1, const float* __restrict__ W2,
    const float* __restrict__ a_s, const float* __restrict__ a_d,
    __half* __restrict__ h2, float* __restrict__ als2, float* __restrict__ ald2)
{
    __shared__ float W2l[F1 * OUTC];   // 8 KB
    for (int i = threadIdx.x; i < F1 * OUTC; i += 256) W2l[i] = W2[i];
    __syncthreads();
    int n = blockIdx.x * blockDim.x + threadIdx.x;
    if (n >= N_NODES) return;

    float o[OUTC];
    #pragma unroll
    for (int c = 0; c < OUTC; ++c) o[c] = 0.f;
    const uint4* xr = (const uint4*)(h1 + (size_t)n * F1);
    for (int k8 = 0; k8 < 16; ++k8) {
        H8 xv; xv.u = xr[k8];
        int k = k8 * 8;
        #pragma unroll
        for (int j = 0; j < 8; ++j) {
            float xf = __half2float(xv.h[j]);
            #pragma unroll
            for (int c = 0; c < OUTC; ++c)
                o[c] = fmaf(xf, W2l[(k + j) * OUTC + c], o[c]);
        }
    }
    H8 s0, s1;
    #pragma unroll
    for (int j = 0; j < 8; ++j) { s0.h[j] = __float2half(o[j]); s1.h[j] = __float2half(o[8 + j]); }
    uint4* h2o = (uint4*)(h2 + (size_t)n * OUTC);
    h2o[0] = s0.u; h2o[1] = s1.u;
    float ps = 0.f, pd = 0.f;
    #pragma unroll
    for (int c = 0; c < OUTC; ++c) { ps += o[c] * a_s[c]; pd += o[c] * a_d[c]; }
    als2[n] = ps; ald2[n] = pd;
}

// ------ Layer 2 gather: 4 lanes/node, 4 fp16 feats/lane, no-max softmax ----
__global__ __launch_bounds__(256) void agg2_kernel(
    const int* __restrict__ rowstart, const int* __restrict__ csr,
    const __half* __restrict__ h2, const float* __restrict__ als,
    const float* __restrict__ ald, const float* __restrict__ b2,
    float* __restrict__ out)
{
    int tid = threadIdx.x;
    int n = blockIdx.x * 64 + (tid >> 2);
    if (n >= N_NODES) return;
    int c = (tid & 3) * 4;
    float aldn = ald[n];
    float v0 = als[n] + aldn;
    v0 = fmaxf(v0, NEG * v0);
    float w0 = __expf(v0);
    float sum = w0;
    H4 hs; hs.u = *(const ushort4*)(h2 + (size_t)n * OUTC + c);
    float a0 = w0 * __half2float(hs.h[0]), a1 = w0 * __half2float(hs.h[1]);
    float a2 = w0 * __half2float(hs.h[2]), a3 = w0 * __half2float(hs.h[3]);
    int r0 = rowstart[n], r1 = rowstart[n + 1];

    int sB = (r0 + 1 < r1) ? csr[r0 + 1] : 0;
    float vN = 0.f; H4 hN; hN.u = make_ushort4(0, 0, 0, 0);
    if (r0 < r1) {
        int sA = csr[r0];
        float t = als[sA] + aldn;
        vN = fmaxf(t, NEG * t);
        hN.u = *(const ushort4*)(h2 + (size_t)sA * OUTC + c);
    }
    for (int k = r0; k < r1; ++k) {
        float v = vN; H4 hv = hN;
        int sC = (k + 2 < r1) ? csr[k + 2] : 0;
        if (k + 1 < r1) {
            float t = als[sB] + aldn;
            vN = fmaxf(t, NEG * t);
            hN.u = *(const ushort4*)(h2 + (size_t)sB * OUTC + c);
        }
        sB = sC;
        float w = __expf(v);
        sum += w;
        a0 = fmaf(w, __half2float(hv.h[0]), a0);
        a1 = fmaf(w, __half2float(hv.h[1]), a1);
        a2 = fmaf(w, __half2float(hv.h[2]), a2);
        a3 = fmaf(w, __half2float(hv.h[3]), a3);
    }
    float inv = 1.0f / sum;
    float4 bv = *(const float4*)(b2 + c);
    float4 o;
    o.x = a0 * inv + bv.x; o.y = a1 * inv + bv.y;
    o.z = a2 * inv + bv.z; o.w = a3 * inv + bv.w;
    *(float4*)(out + (size_t)n * OUTC + c) = o;
}

extern "C" void kernel_launch(void* const* d_in, const int* in_sizes, int n_in,
                              void* d_out, int out_size, void* d_ws, size_t ws_size,
                              hipStream_t stream)
{
    const float* x   = (const float*)d_in[0];
    const int*   ei  = (const int*)  d_in[1];
    const float* W1  = (const float*)d_in[2];
    const float* as1 = (const float*)d_in[3];
    const float* ad1 = (const float*)d_in[4];
    const float* b1  = (const float*)d_in[5];
    const float* W2  = (const float*)d_in[6];
    const float* as2 = (const float*)d_in[7];
    const float* ad2 = (const float*)d_in[8];
    const float* b2  = (const float*)d_in[9];
    float* out = (float*)d_out;

    // workspace carve-up (byte offsets; fp16 blocks first keep 16B alignment)
    char* wsb = (char*)d_ws;
    const size_t SZ_H1 = (size_t)N_NODES * F1 * sizeof(__half);   // 12.8 MB
    __half* h1h = (__half*)wsb;
    __half* h1b = (__half*)(wsb + SZ_H1);
    float*  als1 = (float*)(wsb + 2 * SZ_H1);                     // N*8
    float*  ald1 = als1 + N_NODES * HEADS;                        // N*8
    __half* h2f  = (__half*)(ald1 + N_NODES * HEADS);             // N*16 fp16
    float*  als2 = (float*)(h2f + (size_t)N_NODES * OUTC);        // N
    float*  ald2 = als2 + N_NODES;                                // N
    int2*   tmp  = (int2*)(ald2 + N_NODES);                       // NE int2 (8B-aligned)
    int*    cnt  = (int*)(tmp + NE);                              // NBKT*NPART
    int*    csr  = cnt + NBKT * NPART;                            // NE
    int*    rowstart = csr + NE;                                  // N+1

    // ---- CSR build: locality-friendly two-level counting sort ----
    part_hist   <<<NPART, 256, 0, stream>>>(ei, cnt);
    scan50k     <<<1, 1024, 0, stream>>>(cnt);
    part_scatter<<<NPART, 256, 0, stream>>>(ei, cnt, tmp);
    bucket_sort <<<NBKT, 256, 0, stream>>>(tmp, cnt, rowstart, csr);

    // ---- layer 1 ----
    node1_kernel<<<(N_NODES + 63) / 64, 256, 0, stream>>>(x, W1, as1, ad1, h1h, als1, ald1);
    agg1_kernel<<<N_NODES / 16, 256, 0, stream>>>(rowstart, csr, h1h, als1, ald1, b1, h1b);

    // ---- layer 2 ----
    node2_kernel<<<(N_NODES + 255) / 256, 256, 0, stream>>>(h1b, W2, as2, ad2, h2f, als2, ald2);
    agg2_kernel<<<(N_NODES + 63) / 64, 256, 0, stream>>>(rowstart, csr, h2f, als2, ald2, b2, out);
}